// Round 7
// baseline (232.883 us; speedup 1.0000x reference)
//
#include <hip/hip_runtime.h>
#include <hip/hip_bf16.h>

// MHA block: B=2, L=2048, D=1024, H=16, d_k=64.
// R16: revert gemm body to R13's 2-barrier structure (counted-vmcnt R15 was
// neutral: 64 vs 62 us -- the T4 lever needs the 8-phase role-split which
// needs 256^2 tiles, impossible at N=1024). New lever: kernel-count
// reduction. vtrans is DELETED; the QKV gemm's V-segment (seg==2) writes its
// output directly in Vt[bh][d][L] layout from the epilogue (same 2B store
// count, scatter absorbed by L2), saving the 8MB+8MB Vp round-trip, one
// kernel, and one launch gap. QKV MT=64 (1536 blk), proj MT=32 (1024 blk),
// attn 8-wave R13 -- all byte-identical to R13 except the epilogue flag.

#define D_MODELC 1024
#define N_HEADSC 16
#define D_KC 64
#define BBC 2
#define LLC 2048
#define MMC (BBC * LLC) /* 4096 */

typedef __attribute__((ext_vector_type(8))) short v8s;
typedef __attribute__((ext_vector_type(4))) float v4f;

__device__ __forceinline__ float bf2f(unsigned short u) {
    union { unsigned int i; float f; } x;
    x.i = ((unsigned int)u) << 16;
    return x.f;
}
__device__ __forceinline__ unsigned short f2bf(float f) {
    union { float f; unsigned int i; } x;
    x.f = f;
    unsigned int r = x.i + 0x7fffu + ((x.i >> 16) & 1u);  // RNE
    return (unsigned short)(r >> 16);
}
// packed f32x2 -> bf16x2 (v_cvt_pk_bf16_f32 on gfx950), low short = a
__device__ __forceinline__ unsigned int pk2bf(float a, float b) {
    __hip_bfloat162 h = __float22bfloat162_rn(make_float2(a, b));
    return *(unsigned int*)&h;
}

#define AS1 __attribute__((address_space(1)))
#define AS3 __attribute__((address_space(3)))

// ---------------- weight transpose+convert: Wt[z][n][k] = W_z[k][n] ----------------
__global__ __launch_bounds__(256) void wtrans(const float* __restrict__ w0,
                                              const float* __restrict__ w1,
                                              const float* __restrict__ w2,
                                              const float* __restrict__ w3,
                                              unsigned short* __restrict__ out) {
    __shared__ unsigned short T[64][65];
    const int z = blockIdx.z;
    const float* W = z == 0 ? w0 : (z == 1 ? w1 : (z == 2 ? w2 : w3));
    unsigned short* O = out + (size_t)z * D_MODELC * D_MODELC;
    const int k0 = blockIdx.y * 64, n0 = blockIdx.x * 64;
    const int c = threadIdx.x & 63, r4 = threadIdx.x >> 6;
#pragma unroll
    for (int i = 0; i < 16; i++) {
        int r = i * 4 + r4;
        T[r][c] = f2bf(W[(size_t)(k0 + r) * D_MODELC + n0 + c]);
    }
    __syncthreads();
#pragma unroll
    for (int i = 0; i < 16; i++) {
        int r = i * 4 + r4;
        O[(size_t)(n0 + r) * D_MODELC + k0 + c] = T[c][r];
    }
}

// ---------------- BK=64 GEMM, 2-barrier K-loop, XCD-grouped decode ----------------
// LDS rows are 64 shorts (128B); chunk j of row r lives at slot j^(r&7)
// (swizzle applied on the GLOBAL address for async staging; ds_write path
// writes the swizzled slot directly). Frag reads XOR with sw = m15&7.
// VT_SEG2: seg==2 writes its output tile directly in Vt[bh][d][L] layout
// (b=row>>11, j=row&2047, h=col>>6, d=col&63) -- replaces the vtrans kernel.
template <int MT, int SEGS, bool A_F32, bool OUT_F32, bool VT_SEG2>
__global__ __launch_bounds__(256) void gemm_tile(
    const void* __restrict__ A0, const void* __restrict__ A1, const void* __restrict__ A2,
    const unsigned short* __restrict__ Wt,
    const float* __restrict__ bias0, const float* __restrict__ bias1,
    const float* __restrict__ bias2,
    void* __restrict__ C0, void* __restrict__ C1, void* __restrict__ C2,
    float scale0, float scale1, float scale2) {
    const int K = D_MODELC, N = D_MODELC;
    constexpr int MI = MT / 32;         // MFMA row-tiles per wave
    constexpr int MB = MMC / MT;        // m-tiles
    constexpr int PER = SEGS * MB / 8;  // groups per XCD
    __shared__ __align__(16) unsigned short As[MT * 64];
    __shared__ __align__(16) unsigned short Bs[128 * 64];

    const int t = threadIdx.x;
    const int w = t >> 6, lane = t & 63;
    const int quad = lane >> 4, m15 = lane & 15;
    const int wr = w >> 1, wc = w & 1;
    const int sw = m15 & 7;

    // XCD-grouped decode (8 n-blocks of one (seg,mb) share blockIdx%8)
    const int flat = blockIdx.x;
    const int xcd = flat & 7;
    const int slot0 = flat >> 3;
    const int group = xcd * PER + (slot0 >> 3);
    const int nb = slot0 & 7;
    const int seg = group / MB;
    const int mb = group % MB;
    const int n0 = nb * 128;
    const int m0 = mb * MT;

    const void* Ap = seg == 0 ? A0 : (seg == 1 ? A1 : A2);
    const unsigned short* Wp = Wt + (size_t)seg * D_MODELC * D_MODELC;
    const float* bias = seg == 0 ? bias0 : (seg == 1 ? bias1 : bias2);
    void* Cp = seg == 0 ? C0 : (seg == 1 ? C1 : C2);
    const float scl = seg == 0 ? scale0 : (seg == 1 ? scale1 : scale2);

    v4f acc[MI][4];
#pragma unroll
    for (int mi = 0; mi < MI; mi++)
#pragma unroll
        for (int ni = 0; ni < 4; ni++) acc[mi][ni] = (v4f){0.f, 0.f, 0.f, 0.f};

    for (int k0 = 0; k0 < K; k0 += 64) {
        // B staging: 128 rows x 8 chunks, 4 chunks/thread, async.
        // LDS linear (wave base + lane*16), global chunk = slot ^ (row&7).
#pragma unroll
        for (int i = 0; i < 4; i++) {
            int c = i * 256 + t;
            int row = c >> 3, slot = c & 7;
            int j = slot ^ (row & 7);
            const unsigned short* g = Wp + (size_t)(n0 + row) * K + k0 + j * 8;
            __builtin_amdgcn_global_load_lds(
                (const AS1 unsigned int*)g,
                (AS3 unsigned int*)(Bs + (size_t)c * 8), 16, 0, 0);
        }
        if (A_F32) {
            // fp32 A: vector loads + packed convert + swizzled ds_write
#pragma unroll
            for (int i = 0; i < MT / 32; i++) {
                int c = i * 256 + t;
                int row = c >> 3, slot = c & 7;
                int j = slot ^ (row & 7);
                const float* src = (const float*)Ap + (size_t)(m0 + row) * K + k0 + j * 8;
                float4 f0 = ((const float4*)src)[0];
                float4 f1 = ((const float4*)src)[1];
                uint4 pk;
                pk.x = pk2bf(f0.x, f0.y);
                pk.y = pk2bf(f0.z, f0.w);
                pk.z = pk2bf(f1.x, f1.y);
                pk.w = pk2bf(f1.z, f1.w);
                *(uint4*)&As[(size_t)c * 8] = pk;
            }
        } else {
#pragma unroll
            for (int i = 0; i < MT / 32; i++) {
                int c = i * 256 + t;
                int row = c >> 3, slot = c & 7;
                int j = slot ^ (row & 7);
                const unsigned short* g =
                    (const unsigned short*)Ap + (size_t)(m0 + row) * K + k0 + j * 8;
                __builtin_amdgcn_global_load_lds(
                    (const AS1 unsigned int*)g,
                    (AS3 unsigned int*)(As + (size_t)c * 8), 16, 0, 0);
            }
        }
        __syncthreads();

#pragma unroll
        for (int kk = 0; kk < 2; kk++) {
            v8s a[MI], bfr[4];
#pragma unroll
            for (int mi = 0; mi < MI; mi++)
                a[mi] = *(const v8s*)&As[(wr * (MT / 2) + mi * 16 + m15) * 64 +
                                         (((kk * 4 + quad) ^ sw) * 8)];
#pragma unroll
            for (int ni = 0; ni < 4; ni++)
                bfr[ni] = *(const v8s*)&Bs[(wc * 64 + ni * 16 + m15) * 64 +
                                           (((kk * 4 + quad) ^ sw) * 8)];
#pragma unroll
            for (int mi = 0; mi < MI; mi++)
#pragma unroll
                for (int ni = 0; ni < 4; ni++)
                    acc[mi][ni] = __builtin_amdgcn_mfma_f32_16x16x32_bf16(
                        a[mi], bfr[ni], acc[mi][ni], 0, 0, 0);
        }
        __syncthreads();
    }

#pragma unroll
    for (int ni = 0; ni < 4; ni++) {
        int col = n0 + wc * 64 + ni * 16 + m15;
        float bv = bias[col];
#pragma unroll
        for (int mi = 0; mi < MI; mi++) {
#pragma unroll
            for (int r = 0; r < 4; r++) {
                int row = m0 + wr * (MT / 2) + mi * 16 + quad * 4 + r;
                float v = (acc[mi][ni][r] + bv) * scl;
                if (OUT_F32) {
                    ((float*)Cp)[(size_t)row * N + col] = v;
                } else if (VT_SEG2 && seg == 2) {
                    // direct Vt[bh][d][L] write: replaces vtrans
                    ((unsigned short*)Cp)[(((size_t)(row >> 11) * 16 + (col >> 6)) * 64 +
                                           (col & 63)) * LLC + (row & 2047)] = f2bf(v);
                } else {
                    ((unsigned short*)Cp)[(size_t)row * N + col] = f2bf(v);
                }
            }
        }
    }
}

// ---------------- MFMA flash attention: 8 waves x 16 q-rows (R13) ----------------
__global__ __launch_bounds__(512) void attn_mfma(const unsigned short* __restrict__ Qp,
                                                 const unsigned short* __restrict__ Kp,
                                                 const unsigned short* __restrict__ Vt,
                                                 unsigned short* __restrict__ X) {
    __shared__ __align__(16) unsigned short lds[8192 + 8192 + 128 * 72];
    unsigned short* Kb = lds;
    unsigned short* Vb = lds + 8192;
    unsigned short* PQ = lds + 16384;

    const int t = threadIdx.x;
    const int w = t >> 6, lane = t & 63;
    const int quad = lane >> 4, m15 = lane & 15;
    const int bh = blockIdx.y;
    const int b = bh >> 4, h = bh & 15;
    const int q0 = blockIdx.x * 128;
    const size_t hd = (size_t)h * 64;
    const int sw = m15 & 7;

    // Q staging: 128 rows x 8 chunks = 1024 chunks of 16B, 512 threads -> 2 iters
#pragma unroll
    for (int i = 0; i < 2; i++) {
        int chunk = i * 512 + t;
        int row = chunk >> 3, slot = chunk & 7;
        int j = slot ^ (row & 7);
        const unsigned short* g =
            Qp + ((size_t)(b * LLC + q0 + row)) * D_MODELC + hd + j * 8;
        __builtin_amdgcn_global_load_lds((const AS1 unsigned int*)g,
                                         (AS3 unsigned int*)(PQ + (i * 512 + w * 64) * 8),
                                         16, 0, 0);
    }
    {
        // K tile 0 (sigma row permutation) + V tile 0: 512 chunks each, 1 iter
        int row = t >> 3, slot = t & 7;
        int j = slot ^ (row & 7);
        int gr = 4 * (row & 15) + (row >> 4);  // sigma
        const unsigned short* gk =
            Kp + ((size_t)(b * LLC + 0 + gr)) * D_MODELC + hd + j * 8;
        __builtin_amdgcn_global_load_lds((const AS1 unsigned int*)gk,
                                         (AS3 unsigned int*)(Kb + (w * 64) * 8), 16, 0, 0);
        const unsigned short* gv = Vt + ((size_t)(bh * 64 + row)) * LLC + 0 + j * 8;
        __builtin_amdgcn_global_load_lds((const AS1 unsigned int*)gv,
                                         (AS3 unsigned int*)(Vb + (w * 64) * 8), 16, 0, 0);
    }
    __syncthreads();

    v8s qa[2];
#pragma unroll
    for (int kk = 0; kk < 2; kk++)
        qa[kk] = *(const v8s*)&PQ[(w * 16 + m15) * 64 + (((kk * 4 + quad) ^ sw) * 8)];
    __syncthreads();

    v8s ones;
#pragma unroll
    for (int u = 0; u < 8; u++) ones[u] = (short)0x3F80;  // bf16 1.0

    v4f O[4];
#pragma unroll
    for (int db = 0; db < 4; db++) O[db] = (v4f){0.f, 0.f, 0.f, 0.f};
    v4f lacc = (v4f){0.f, 0.f, 0.f, 0.f};

    for (int it = 0; it < 32; it++) {
        const int cur = it & 1;
        unsigned short* Kc = Kb + cur * 4096;
        unsigned short* Vc = Vb + cur * 4096;
        if (it < 31) {
            unsigned short* Kn = Kb + (cur ^ 1) * 4096;
            unsigned short* Vn = Vb + (cur ^ 1) * 4096;
            const int k0n = (it + 1) * 64;
            int row = t >> 3, slot = t & 7;
            int j = slot ^ (row & 7);
            int gr = 4 * (row & 15) + (row >> 4);
            const unsigned short* gk =
                Kp + ((size_t)(b * LLC + k0n + gr)) * D_MODELC + hd + j * 8;
            __builtin_amdgcn_global_load_lds((const AS1 unsigned int*)gk,
                                             (AS3 unsigned int*)(Kn + (w * 64) * 8), 16, 0, 0);
            const unsigned short* gv = Vt + ((size_t)(bh * 64 + row)) * LLC + k0n + j * 8;
            __builtin_amdgcn_global_load_lds((const AS1 unsigned int*)gv,
                                             (AS3 unsigned int*)(Vn + (w * 64) * 8), 16, 0, 0);
        }

        v4f S[4];
#pragma unroll
        for (int ns = 0; ns < 4; ns++) S[ns] = (v4f){0.f, 0.f, 0.f, 0.f};
#pragma unroll
        for (int kk = 0; kk < 2; kk++) {
#pragma unroll
            for (int ns = 0; ns < 4; ns++) {
                v8s kf = *(const v8s*)&Kc[(ns * 16 + m15) * 64 +
                                          (((kk * 4 + quad) ^ sw) * 8)];
                S[ns] = __builtin_amdgcn_mfma_f32_16x16x32_bf16(qa[kk], kf, S[ns], 0, 0, 0);
            }
        }

#pragma unroll
        for (int r = 0; r < 4; r++) {
            int prow = w * 16 + quad * 4 + r;
            float e0 = __builtin_amdgcn_exp2f(S[0][r]);
            float e1 = __builtin_amdgcn_exp2f(S[1][r]);
            float e2 = __builtin_amdgcn_exp2f(S[2][r]);
            float e3 = __builtin_amdgcn_exp2f(S[3][r]);
            uint2 pk;
            pk.x = pk2bf(e0, e1);
            pk.y = pk2bf(e2, e3);
            *(uint2*)&PQ[prow * 72 + 4 * m15] = pk;
        }

#pragma unroll
        for (int kk = 0; kk < 2; kk++) {
            v8s a0 = *(const v8s*)&PQ[(w * 16 + m15) * 72 + kk * 32 + quad * 8];
            lacc = __builtin_amdgcn_mfma_f32_16x16x32_bf16(a0, ones, lacc, 0, 0, 0);
#pragma unroll
            for (int db = 0; db < 4; db++) {
                v8s vf = *(const v8s*)&Vc[(db * 16 + m15) * 64 +
                                          (((kk * 4 + quad) ^ sw) * 8)];
                O[db] = __builtin_amdgcn_mfma_f32_16x16x32_bf16(a0, vf, O[db], 0, 0, 0);
            }
        }
        __syncthreads();
    }

#pragma unroll
    for (int r = 0; r < 4; r++) {
        float inv = 1.f / lacc[r];
        int row = q0 + w * 16 + quad * 4 + r;
#pragma unroll
        for (int db = 0; db < 4; db++) {
            X[((size_t)(b * LLC + row)) * D_MODELC + hd + db * 16 + m15] =
                f2bf(O[db][r] * inv);
        }
    }
}

extern "C" void kernel_launch(void* const* d_in, const int* in_sizes, int n_in,
                              void* d_out, int out_size, void* d_ws, size_t ws_size,
                              hipStream_t stream) {
    const float* q = (const float*)d_in[0];
    const float* k = (const float*)d_in[1];
    const float* v = (const float*)d_in[2];
    const float* w_q = (const float*)d_in[3];
    const float* b_q = (const float*)d_in[4];
    const float* w_k = (const float*)d_in[5];
    const float* b_k = (const float*)d_in[6];
    const float* w_v = (const float*)d_in[7];
    const float* b_v = (const float*)d_in[8];
    const float* w_o = (const float*)d_in[9];
    const float* b_o = (const float*)d_in[10];

    const size_t elems = (size_t)MMC * D_MODELC;  // 4M elems = 8MB bf16
    unsigned short* Qp = (unsigned short*)d_ws;   // X aliases Qp (see attn)
    unsigned short* Kp = Qp + elems;
    unsigned short* Vp = Kp + elems;              // unused (V writes go to Vt)
    unsigned short* Wt = Vp + elems;  // 4 x 1024x1024 bf16 = 8MB (q,k,v,o)
    unsigned short* X = Qp;
    unsigned short* Vt = (unsigned short*)d_out;  // scratch until final GEMM

    const float QSCALE = 0.125f * 1.44269504088896340736f;  // 1/sqrt(64)*log2(e)

    wtrans<<<dim3(16, 16, 4), 256, 0, stream>>>(w_q, w_k, w_v, w_o, Wt);

    // QKV: 3 segs x 64 m-tiles x 8 n-blocks = 1536 blocks, MT=64.
    // seg==2 (V) writes directly into Vt layout (d_out scratch).
    gemm_tile<64, 3, true, false, true><<<1536, 256, 0, stream>>>(
        q, k, v, Wt, b_q, b_k, b_v, Qp, Kp, Vt, QSCALE, 1.f, 1.f);

    attn_mfma<<<dim3(LLC / 128, BBC * N_HEADSC), 512, 0, stream>>>(Qp, Kp, Vt, X);

    // final: 1 seg x 128 m-tiles x 8 n-blocks = 1024 blocks, MT=32
    gemm_tile<32, 1, false, true, false><<<1024, 256, 0, stream>>>(
        X, X, X, Wt + (size_t)3 * D_MODELC * D_MODELC, b_o, b_o, b_o,
        d_out, d_out, d_out, 1.f, 1.f, 1.f);
}

// Round 8
// 225.783 us; speedup vs baseline: 1.0314x; 1.0314x over previous
//
#include <hip/hip_runtime.h>
#include <hip/hip_bf16.h>

// MHA block: B=2, L=2048, D=1024, H=16, d_k=64.
// R17: fix R16's Vt scatter. seg==2 (V) epilogue now transposes through LDS
// (As/Bs dead after the K-loop; 64x128 tile = 16KB fits): acc -> T[col][row]
// -> barrier -> v8s reads along rows -> 16B coalesced stores along the L dim
// of Vt[bh][d][L]. Replaces R16's 2B/4KB-stride scatter (which cost +15us and
// +3.5MB write amplification). vtrans stays deleted. gemm K-loop (2-barrier
// R13 body), attn (8-wave R13), wtrans unchanged. QKV MT=64 1536 blk,
// proj MT=32 1024 blk.

#define D_MODELC 1024
#define N_HEADSC 16
#define D_KC 64
#define BBC 2
#define LLC 2048
#define MMC (BBC * LLC) /* 4096 */

typedef __attribute__((ext_vector_type(8))) short v8s;
typedef __attribute__((ext_vector_type(4))) float v4f;

__device__ __forceinline__ float bf2f(unsigned short u) {
    union { unsigned int i; float f; } x;
    x.i = ((unsigned int)u) << 16;
    return x.f;
}
__device__ __forceinline__ unsigned short f2bf(float f) {
    union { float f; unsigned int i; } x;
    x.f = f;
    unsigned int r = x.i + 0x7fffu + ((x.i >> 16) & 1u);  // RNE
    return (unsigned short)(r >> 16);
}
// packed f32x2 -> bf16x2 (v_cvt_pk_bf16_f32 on gfx950), low short = a
__device__ __forceinline__ unsigned int pk2bf(float a, float b) {
    __hip_bfloat162 h = __float22bfloat162_rn(make_float2(a, b));
    return *(unsigned int*)&h;
}

#define AS1 __attribute__((address_space(1)))
#define AS3 __attribute__((address_space(3)))

// ---------------- weight transpose+convert: Wt[z][n][k] = W_z[k][n] ----------------
__global__ __launch_bounds__(256) void wtrans(const float* __restrict__ w0,
                                              const float* __restrict__ w1,
                                              const float* __restrict__ w2,
                                              const float* __restrict__ w3,
                                              unsigned short* __restrict__ out) {
    __shared__ unsigned short T[64][65];
    const int z = blockIdx.z;
    const float* W = z == 0 ? w0 : (z == 1 ? w1 : (z == 2 ? w2 : w3));
    unsigned short* O = out + (size_t)z * D_MODELC * D_MODELC;
    const int k0 = blockIdx.y * 64, n0 = blockIdx.x * 64;
    const int c = threadIdx.x & 63, r4 = threadIdx.x >> 6;
#pragma unroll
    for (int i = 0; i < 16; i++) {
        int r = i * 4 + r4;
        T[r][c] = f2bf(W[(size_t)(k0 + r) * D_MODELC + n0 + c]);
    }
    __syncthreads();
#pragma unroll
    for (int i = 0; i < 16; i++) {
        int r = i * 4 + r4;
        O[(size_t)(n0 + r) * D_MODELC + k0 + c] = T[c][r];
    }
}

// ---------------- BK=64 GEMM, 2-barrier K-loop, XCD-grouped decode ----------------
// LDS rows are 64 shorts (128B); chunk j of row r lives at slot j^(r&7)
// (swizzle applied on the GLOBAL address for async staging; ds_write path
// writes the swizzled slot directly). Frag reads XOR with sw = m15&7.
// VT_SEG2: seg==2 routes its output through an LDS transpose and writes
// Vt[bh][d][L] with 16B coalesced stores -- replaces the vtrans kernel.
template <int MT, int SEGS, bool A_F32, bool OUT_F32, bool VT_SEG2>
__global__ __launch_bounds__(256) void gemm_tile(
    const void* __restrict__ A0, const void* __restrict__ A1, const void* __restrict__ A2,
    const unsigned short* __restrict__ Wt,
    const float* __restrict__ bias0, const float* __restrict__ bias1,
    const float* __restrict__ bias2,
    void* __restrict__ C0, void* __restrict__ C1, void* __restrict__ C2,
    float scale0, float scale1, float scale2) {
    const int K = D_MODELC, N = D_MODELC;
    constexpr int MI = MT / 32;         // MFMA row-tiles per wave
    constexpr int MB = MMC / MT;        // m-tiles
    constexpr int PER = SEGS * MB / 8;  // groups per XCD
    // As/Bs share one allocation; the V-epilogue transpose tile T (128x68
    // shorts = 17KB) overlays it after the K-loop (both dead by then).
    __shared__ __align__(16) unsigned short SMEM[MT * 64 + 128 * 64];
    unsigned short* As = SMEM;
    unsigned short* Bs = SMEM + MT * 64;

    const int t = threadIdx.x;
    const int w = t >> 6, lane = t & 63;
    const int quad = lane >> 4, m15 = lane & 15;
    const int wr = w >> 1, wc = w & 1;
    const int sw = m15 & 7;

    // XCD-grouped decode (8 n-blocks of one (seg,mb) share blockIdx%8)
    const int flat = blockIdx.x;
    const int xcd = flat & 7;
    const int slot0 = flat >> 3;
    const int group = xcd * PER + (slot0 >> 3);
    const int nb = slot0 & 7;
    const int seg = group / MB;
    const int mb = group % MB;
    const int n0 = nb * 128;
    const int m0 = mb * MT;

    const void* Ap = seg == 0 ? A0 : (seg == 1 ? A1 : A2);
    const unsigned short* Wp = Wt + (size_t)seg * D_MODELC * D_MODELC;
    const float* bias = seg == 0 ? bias0 : (seg == 1 ? bias1 : bias2);
    void* Cp = seg == 0 ? C0 : (seg == 1 ? C1 : C2);
    const float scl = seg == 0 ? scale0 : (seg == 1 ? scale1 : scale2);

    v4f acc[MI][4];
#pragma unroll
    for (int mi = 0; mi < MI; mi++)
#pragma unroll
        for (int ni = 0; ni < 4; ni++) acc[mi][ni] = (v4f){0.f, 0.f, 0.f, 0.f};

    for (int k0 = 0; k0 < K; k0 += 64) {
        // B staging: 128 rows x 8 chunks, 4 chunks/thread, async.
        // LDS linear (wave base + lane*16), global chunk = slot ^ (row&7).
#pragma unroll
        for (int i = 0; i < 4; i++) {
            int c = i * 256 + t;
            int row = c >> 3, slot = c & 7;
            int j = slot ^ (row & 7);
            const unsigned short* g = Wp + (size_t)(n0 + row) * K + k0 + j * 8;
            __builtin_amdgcn_global_load_lds(
                (const AS1 unsigned int*)g,
                (AS3 unsigned int*)(Bs + (size_t)c * 8), 16, 0, 0);
        }
        if (A_F32) {
            // fp32 A: vector loads + packed convert + swizzled ds_write
#pragma unroll
            for (int i = 0; i < MT / 32; i++) {
                int c = i * 256 + t;
                int row = c >> 3, slot = c & 7;
                int j = slot ^ (row & 7);
                const float* src = (const float*)Ap + (size_t)(m0 + row) * K + k0 + j * 8;
                float4 f0 = ((const float4*)src)[0];
                float4 f1 = ((const float4*)src)[1];
                uint4 pk;
                pk.x = pk2bf(f0.x, f0.y);
                pk.y = pk2bf(f0.z, f0.w);
                pk.z = pk2bf(f1.x, f1.y);
                pk.w = pk2bf(f1.z, f1.w);
                *(uint4*)&As[(size_t)c * 8] = pk;
            }
        } else {
#pragma unroll
            for (int i = 0; i < MT / 32; i++) {
                int c = i * 256 + t;
                int row = c >> 3, slot = c & 7;
                int j = slot ^ (row & 7);
                const unsigned short* g =
                    (const unsigned short*)Ap + (size_t)(m0 + row) * K + k0 + j * 8;
                __builtin_amdgcn_global_load_lds(
                    (const AS1 unsigned int*)g,
                    (AS3 unsigned int*)(As + (size_t)c * 8), 16, 0, 0);
            }
        }
        __syncthreads();

#pragma unroll
        for (int kk = 0; kk < 2; kk++) {
            v8s a[MI], bfr[4];
#pragma unroll
            for (int mi = 0; mi < MI; mi++)
                a[mi] = *(const v8s*)&As[(wr * (MT / 2) + mi * 16 + m15) * 64 +
                                         (((kk * 4 + quad) ^ sw) * 8)];
#pragma unroll
            for (int ni = 0; ni < 4; ni++)
                bfr[ni] = *(const v8s*)&Bs[(wc * 64 + ni * 16 + m15) * 64 +
                                           (((kk * 4 + quad) ^ sw) * 8)];
#pragma unroll
            for (int mi = 0; mi < MI; mi++)
#pragma unroll
                for (int ni = 0; ni < 4; ni++)
                    acc[mi][ni] = __builtin_amdgcn_mfma_f32_16x16x32_bf16(
                        a[mi], bfr[ni], acc[mi][ni], 0, 0, 0);
        }
        __syncthreads();
    }

    if (VT_SEG2 && seg == 2) {
        // ---- V epilogue: LDS transpose, then coalesced Vt[bh][d][L] writes.
        // After the K-loop's final barrier, As/Bs are dead; overlay T[128][68].
        unsigned short* T = SMEM;
#pragma unroll
        for (int ni = 0; ni < 4; ni++) {
            int colc = wc * 64 + ni * 16 + m15;
            float bv = bias[n0 + colc];
#pragma unroll
            for (int mi = 0; mi < MI; mi++) {
#pragma unroll
                for (int r = 0; r < 4; r++) {
                    int rowc = wr * (MT / 2) + mi * 16 + quad * 4 + r;
                    T[colc * 68 + rowc] = f2bf((acc[mi][ni][r] + bv) * scl);
                }
            }
        }
        __syncthreads();
        const int b0 = m0 >> 11;       // batch of this m-tile (MT=64 < 2048)
        const int j0 = m0 & 2047;      // token base within batch
#pragma unroll
        for (int i = 0; i < MT / 16; i++) {  // 128 rows x 8 chunks / 256 thr
            int c = i * 256 + t;
            int rho = c >> 3, jc = c & 7;    // rho = local col (h,d), jc = j chunk
            v8s val = *(const v8s*)&T[rho * 68 + jc * 8];
            int colg = n0 + rho;
            int h = colg >> 6, d = colg & 63;
            *(v8s*)&((unsigned short*)Cp)[(((size_t)(b0 * 16 + h)) * 64 + d) * LLC +
                                          j0 + jc * 8] = val;
        }
        return;
    }

#pragma unroll
    for (int ni = 0; ni < 4; ni++) {
        int col = n0 + wc * 64 + ni * 16 + m15;
        float bv = bias[col];
#pragma unroll
        for (int mi = 0; mi < MI; mi++) {
#pragma unroll
            for (int r = 0; r < 4; r++) {
                int row = m0 + wr * (MT / 2) + mi * 16 + quad * 4 + r;
                float v = (acc[mi][ni][r] + bv) * scl;
                if (OUT_F32)
                    ((float*)Cp)[(size_t)row * N + col] = v;
                else
                    ((unsigned short*)Cp)[(size_t)row * N + col] = f2bf(v);
            }
        }
    }
}

// ---------------- MFMA flash attention: 8 waves x 16 q-rows (R13) ----------------
__global__ __launch_bounds__(512) void attn_mfma(const unsigned short* __restrict__ Qp,
                                                 const unsigned short* __restrict__ Kp,
                                                 const unsigned short* __restrict__ Vt,
                                                 unsigned short* __restrict__ X) {
    __shared__ __align__(16) unsigned short lds[8192 + 8192 + 128 * 72];
    unsigned short* Kb = lds;
    unsigned short* Vb = lds + 8192;
    unsigned short* PQ = lds + 16384;

    const int t = threadIdx.x;
    const int w = t >> 6, lane = t & 63;
    const int quad = lane >> 4, m15 = lane & 15;
    const int bh = blockIdx.y;
    const int b = bh >> 4, h = bh & 15;
    const int q0 = blockIdx.x * 128;
    const size_t hd = (size_t)h * 64;
    const int sw = m15 & 7;

    // Q staging: 128 rows x 8 chunks = 1024 chunks of 16B, 512 threads -> 2 iters
#pragma unroll
    for (int i = 0; i < 2; i++) {
        int chunk = i * 512 + t;
        int row = chunk >> 3, slot = chunk & 7;
        int j = slot ^ (row & 7);
        const unsigned short* g =
            Qp + ((size_t)(b * LLC + q0 + row)) * D_MODELC + hd + j * 8;
        __builtin_amdgcn_global_load_lds((const AS1 unsigned int*)g,
                                         (AS3 unsigned int*)(PQ + (i * 512 + w * 64) * 8),
                                         16, 0, 0);
    }
    {
        // K tile 0 (sigma row permutation) + V tile 0: 512 chunks each, 1 iter
        int row = t >> 3, slot = t & 7;
        int j = slot ^ (row & 7);
        int gr = 4 * (row & 15) + (row >> 4);  // sigma
        const unsigned short* gk =
            Kp + ((size_t)(b * LLC + 0 + gr)) * D_MODELC + hd + j * 8;
        __builtin_amdgcn_global_load_lds((const AS1 unsigned int*)gk,
                                         (AS3 unsigned int*)(Kb + (w * 64) * 8), 16, 0, 0);
        const unsigned short* gv = Vt + ((size_t)(bh * 64 + row)) * LLC + 0 + j * 8;
        __builtin_amdgcn_global_load_lds((const AS1 unsigned int*)gv,
                                         (AS3 unsigned int*)(Vb + (w * 64) * 8), 16, 0, 0);
    }
    __syncthreads();

    v8s qa[2];
#pragma unroll
    for (int kk = 0; kk < 2; kk++)
        qa[kk] = *(const v8s*)&PQ[(w * 16 + m15) * 64 + (((kk * 4 + quad) ^ sw) * 8)];
    __syncthreads();

    v8s ones;
#pragma unroll
    for (int u = 0; u < 8; u++) ones[u] = (short)0x3F80;  // bf16 1.0

    v4f O[4];
#pragma unroll
    for (int db = 0; db < 4; db++) O[db] = (v4f){0.f, 0.f, 0.f, 0.f};
    v4f lacc = (v4f){0.f, 0.f, 0.f, 0.f};

    for (int it = 0; it < 32; it++) {
        const int cur = it & 1;
        unsigned short* Kc = Kb + cur * 4096;
        unsigned short* Vc = Vb + cur * 4096;
        if (it < 31) {
            unsigned short* Kn = Kb + (cur ^ 1) * 4096;
            unsigned short* Vn = Vb + (cur ^ 1) * 4096;
            const int k0n = (it + 1) * 64;
            int row = t >> 3, slot = t & 7;
            int j = slot ^ (row & 7);
            int gr = 4 * (row & 15) + (row >> 4);
            const unsigned short* gk =
                Kp + ((size_t)(b * LLC + k0n + gr)) * D_MODELC + hd + j * 8;
            __builtin_amdgcn_global_load_lds((const AS1 unsigned int*)gk,
                                             (AS3 unsigned int*)(Kn + (w * 64) * 8), 16, 0, 0);
            const unsigned short* gv = Vt + ((size_t)(bh * 64 + row)) * LLC + k0n + j * 8;
            __builtin_amdgcn_global_load_lds((const AS1 unsigned int*)gv,
                                             (AS3 unsigned int*)(Vn + (w * 64) * 8), 16, 0, 0);
        }

        v4f S[4];
#pragma unroll
        for (int ns = 0; ns < 4; ns++) S[ns] = (v4f){0.f, 0.f, 0.f, 0.f};
#pragma unroll
        for (int kk = 0; kk < 2; kk++) {
#pragma unroll
            for (int ns = 0; ns < 4; ns++) {
                v8s kf = *(const v8s*)&Kc[(ns * 16 + m15) * 64 +
                                          (((kk * 4 + quad) ^ sw) * 8)];
                S[ns] = __builtin_amdgcn_mfma_f32_16x16x32_bf16(qa[kk], kf, S[ns], 0, 0, 0);
            }
        }

#pragma unroll
        for (int r = 0; r < 4; r++) {
            int prow = w * 16 + quad * 4 + r;
            float e0 = __builtin_amdgcn_exp2f(S[0][r]);
            float e1 = __builtin_amdgcn_exp2f(S[1][r]);
            float e2 = __builtin_amdgcn_exp2f(S[2][r]);
            float e3 = __builtin_amdgcn_exp2f(S[3][r]);
            uint2 pk;
            pk.x = pk2bf(e0, e1);
            pk.y = pk2bf(e2, e3);
            *(uint2*)&PQ[prow * 72 + 4 * m15] = pk;
        }

#pragma unroll
        for (int kk = 0; kk < 2; kk++) {
            v8s a0 = *(const v8s*)&PQ[(w * 16 + m15) * 72 + kk * 32 + quad * 8];
            lacc = __builtin_amdgcn_mfma_f32_16x16x32_bf16(a0, ones, lacc, 0, 0, 0);
#pragma unroll
            for (int db = 0; db < 4; db++) {
                v8s vf = *(const v8s*)&Vc[(db * 16 + m15) * 64 +
                                          (((kk * 4 + quad) ^ sw) * 8)];
                O[db] = __builtin_amdgcn_mfma_f32_16x16x32_bf16(a0, vf, O[db], 0, 0, 0);
            }
        }
        __syncthreads();
    }

#pragma unroll
    for (int r = 0; r < 4; r++) {
        float inv = 1.f / lacc[r];
        int row = q0 + w * 16 + quad * 4 + r;
#pragma unroll
        for (int db = 0; db < 4; db++) {
            X[((size_t)(b * LLC + row)) * D_MODELC + hd + db * 16 + m15] =
                f2bf(O[db][r] * inv);
        }
    }
}

extern "C" void kernel_launch(void* const* d_in, const int* in_sizes, int n_in,
                              void* d_out, int out_size, void* d_ws, size_t ws_size,
                              hipStream_t stream) {
    const float* q = (const float*)d_in[0];
    const float* k = (const float*)d_in[1];
    const float* v = (const float*)d_in[2];
    const float* w_q = (const float*)d_in[3];
    const float* b_q = (const float*)d_in[4];
    const float* w_k = (const float*)d_in[5];
    const float* b_k = (const float*)d_in[6];
    const float* w_v = (const float*)d_in[7];
    const float* b_v = (const float*)d_in[8];
    const float* w_o = (const float*)d_in[9];
    const float* b_o = (const float*)d_in[10];

    const size_t elems = (size_t)MMC * D_MODELC;  // 4M elems = 8MB bf16
    unsigned short* Qp = (unsigned short*)d_ws;   // X aliases Qp (see attn)
    unsigned short* Kp = Qp + elems;
    unsigned short* Vp = Kp + elems;              // unused (V writes go to Vt)
    unsigned short* Wt = Vp + elems;  // 4 x 1024x1024 bf16 = 8MB (q,k,v,o)
    unsigned short* X = Qp;
    unsigned short* Vt = (unsigned short*)d_out;  // scratch until final GEMM

    const float QSCALE = 0.125f * 1.44269504088896340736f;  // 1/sqrt(64)*log2(e)

    wtrans<<<dim3(16, 16, 4), 256, 0, stream>>>(w_q, w_k, w_v, w_o, Wt);

    // QKV: 3 segs x 64 m-tiles x 8 n-blocks = 1536 blocks, MT=64.
    // seg==2 (V) writes directly into Vt layout (d_out scratch) via LDS
    // transpose epilogue.
    gemm_tile<64, 3, true, false, true><<<1536, 256, 0, stream>>>(
        q, k, v, Wt, b_q, b_k, b_v, Qp, Kp, Vt, QSCALE, 1.f, 1.f);

    attn_mfma<<<dim3(LLC / 128, BBC * N_HEADSC), 512, 0, stream>>>(Qp, Kp, Vt, X);

    // final: 1 seg x 128 m-tiles x 8 n-blocks = 1024 blocks, MT=32
    gemm_tile<32, 1, false, true, false><<<1024, 256, 0, stream>>>(
        X, X, X, Wt + (size_t)3 * D_MODELC * D_MODELC, b_o, b_o, b_o,
        d_out, d_out, d_out, 1.f, 1.f, 1.f);
}

// Round 9
// 220.711 us; speedup vs baseline: 1.0552x; 1.0230x over previous
//
#include <hip/hip_runtime.h>
#include <hip/hip_bf16.h>

// MHA block: B=2, L=2048, D=1024, H=16, d_k=64.
// R18: BK=128 (8 K-steps instead of 16). Three scheduling attacks on the
// per-step __syncthreads drain failed (R10/R11/R14); this reduces the NUMBER
// of drains instead: 16x(drain+230cy) -> 8x(drain+460cy) ~= -40% stall.
// QKV: MT=64 BK=128, LDS 48KB (3/CU). proj: MT=32 BK=128, 40KB (4/CU).
// XOR chunk swizzle acts on low-3 chunk bits (row&7) -- 256B rows keep the
// conflict-free profile. K-loop body, V-epilogue LDS transpose (R17), attn
// (8-wave R13), wtrans unchanged.

#define D_MODELC 1024
#define N_HEADSC 16
#define D_KC 64
#define BBC 2
#define LLC 2048
#define MMC (BBC * LLC) /* 4096 */

typedef __attribute__((ext_vector_type(8))) short v8s;
typedef __attribute__((ext_vector_type(4))) float v4f;

__device__ __forceinline__ float bf2f(unsigned short u) {
    union { unsigned int i; float f; } x;
    x.i = ((unsigned int)u) << 16;
    return x.f;
}
__device__ __forceinline__ unsigned short f2bf(float f) {
    union { float f; unsigned int i; } x;
    x.f = f;
    unsigned int r = x.i + 0x7fffu + ((x.i >> 16) & 1u);  // RNE
    return (unsigned short)(r >> 16);
}
// packed f32x2 -> bf16x2 (v_cvt_pk_bf16_f32 on gfx950), low short = a
__device__ __forceinline__ unsigned int pk2bf(float a, float b) {
    __hip_bfloat162 h = __float22bfloat162_rn(make_float2(a, b));
    return *(unsigned int*)&h;
}

#define AS1 __attribute__((address_space(1)))
#define AS3 __attribute__((address_space(3)))

// ---------------- weight transpose+convert: Wt[z][n][k] = W_z[k][n] ----------------
__global__ __launch_bounds__(256) void wtrans(const float* __restrict__ w0,
                                              const float* __restrict__ w1,
                                              const float* __restrict__ w2,
                                              const float* __restrict__ w3,
                                              unsigned short* __restrict__ out) {
    __shared__ unsigned short T[64][65];
    const int z = blockIdx.z;
    const float* W = z == 0 ? w0 : (z == 1 ? w1 : (z == 2 ? w2 : w3));
    unsigned short* O = out + (size_t)z * D_MODELC * D_MODELC;
    const int k0 = blockIdx.y * 64, n0 = blockIdx.x * 64;
    const int c = threadIdx.x & 63, r4 = threadIdx.x >> 6;
#pragma unroll
    for (int i = 0; i < 16; i++) {
        int r = i * 4 + r4;
        T[r][c] = f2bf(W[(size_t)(k0 + r) * D_MODELC + n0 + c]);
    }
    __syncthreads();
#pragma unroll
    for (int i = 0; i < 16; i++) {
        int r = i * 4 + r4;
        O[(size_t)(n0 + r) * D_MODELC + k0 + c] = T[c][r];
    }
}

// ---------------- GEMM, 2-barrier K-loop, BK-templated, XCD-grouped ----------------
// LDS rows are BK shorts; chunk slot s of row r lives at global chunk
// j = (s & ~7) | ((s&7) ^ (r&7)) (swizzle on the GLOBAL address for async
// staging / ds_write slot). Frag reads use chunk ^ sw with sw = m15&7 (low-3
// bits only, so the identity holds for chunk >= 8 too).
// VT_SEG2: seg==2 routes its output through an LDS transpose and writes
// Vt[bh][d][L] with 16B coalesced stores -- replaces the vtrans kernel.
template <int MT, int BK, int SEGS, bool A_F32, bool OUT_F32, bool VT_SEG2>
__global__ __launch_bounds__(256) void gemm_tile(
    const void* __restrict__ A0, const void* __restrict__ A1, const void* __restrict__ A2,
    const unsigned short* __restrict__ Wt,
    const float* __restrict__ bias0, const float* __restrict__ bias1,
    const float* __restrict__ bias2,
    void* __restrict__ C0, void* __restrict__ C1, void* __restrict__ C2,
    float scale0, float scale1, float scale2) {
    const int K = D_MODELC, N = D_MODELC;
    constexpr int MI = MT / 32;          // MFMA row-tiles per wave
    constexpr int MB = MMC / MT;         // m-tiles
    constexpr int PER = SEGS * MB / 8;   // groups per XCD
    constexpr int CPR = BK / 8;          // 16B chunks per LDS row
    constexpr int BIT = 128 * CPR / 256; // B staging iters per K-step
    constexpr int AIT = MT * CPR / 256;  // A staging iters per K-step
    // As/Bs share one allocation; the V-epilogue transpose tile T (128x68
    // shorts) overlays it after the K-loop (both dead by then).
    __shared__ __align__(16) unsigned short SMEM[MT * BK + 128 * BK];
    unsigned short* As = SMEM;
    unsigned short* Bs = SMEM + MT * BK;

    const int t = threadIdx.x;
    const int w = t >> 6, lane = t & 63;
    const int quad = lane >> 4, m15 = lane & 15;
    const int wr = w >> 1, wc = w & 1;
    const int sw = m15 & 7;

    // XCD-grouped decode (8 n-blocks of one (seg,mb) share blockIdx%8)
    const int flat = blockIdx.x;
    const int xcd = flat & 7;
    const int slot0 = flat >> 3;
    const int group = xcd * PER + (slot0 >> 3);
    const int nb = slot0 & 7;
    const int seg = group / MB;
    const int mb = group % MB;
    const int n0 = nb * 128;
    const int m0 = mb * MT;

    const void* Ap = seg == 0 ? A0 : (seg == 1 ? A1 : A2);
    const unsigned short* Wp = Wt + (size_t)seg * D_MODELC * D_MODELC;
    const float* bias = seg == 0 ? bias0 : (seg == 1 ? bias1 : bias2);
    void* Cp = seg == 0 ? C0 : (seg == 1 ? C1 : C2);
    const float scl = seg == 0 ? scale0 : (seg == 1 ? scale1 : scale2);

    v4f acc[MI][4];
#pragma unroll
    for (int mi = 0; mi < MI; mi++)
#pragma unroll
        for (int ni = 0; ni < 4; ni++) acc[mi][ni] = (v4f){0.f, 0.f, 0.f, 0.f};

    for (int k0 = 0; k0 < K; k0 += BK) {
        // B staging: 128 rows x CPR chunks, async direct-to-LDS.
        // LDS linear (wave base + lane*16), global chunk j = swizzled slot.
#pragma unroll
        for (int i = 0; i < BIT; i++) {
            int c = i * 256 + t;
            int row = c / CPR, slot = c % CPR;
            int j = (slot & ~7) | ((slot & 7) ^ (row & 7));
            const unsigned short* g = Wp + (size_t)(n0 + row) * K + k0 + j * 8;
            __builtin_amdgcn_global_load_lds(
                (const AS1 unsigned int*)g,
                (AS3 unsigned int*)(Bs + (size_t)c * 8), 16, 0, 0);
        }
        if (A_F32) {
            // fp32 A: vector loads + packed convert + swizzled ds_write
#pragma unroll
            for (int i = 0; i < AIT; i++) {
                int c = i * 256 + t;
                int row = c / CPR, slot = c % CPR;
                int j = (slot & ~7) | ((slot & 7) ^ (row & 7));
                const float* src = (const float*)Ap + (size_t)(m0 + row) * K + k0 + j * 8;
                float4 f0 = ((const float4*)src)[0];
                float4 f1 = ((const float4*)src)[1];
                uint4 pk;
                pk.x = pk2bf(f0.x, f0.y);
                pk.y = pk2bf(f0.z, f0.w);
                pk.z = pk2bf(f1.x, f1.y);
                pk.w = pk2bf(f1.z, f1.w);
                *(uint4*)&As[(size_t)c * 8] = pk;
            }
        } else {
#pragma unroll
            for (int i = 0; i < AIT; i++) {
                int c = i * 256 + t;
                int row = c / CPR, slot = c % CPR;
                int j = (slot & ~7) | ((slot & 7) ^ (row & 7));
                const unsigned short* g =
                    (const unsigned short*)Ap + (size_t)(m0 + row) * K + k0 + j * 8;
                __builtin_amdgcn_global_load_lds(
                    (const AS1 unsigned int*)g,
                    (AS3 unsigned int*)(As + (size_t)c * 8), 16, 0, 0);
            }
        }
        __syncthreads();

#pragma unroll
        for (int kk = 0; kk < BK / 32; kk++) {
            v8s a[MI], bfr[4];
#pragma unroll
            for (int mi = 0; mi < MI; mi++)
                a[mi] = *(const v8s*)&As[(wr * (MT / 2) + mi * 16 + m15) * BK +
                                         (((kk * 4 + quad) ^ sw) * 8)];
#pragma unroll
            for (int ni = 0; ni < 4; ni++)
                bfr[ni] = *(const v8s*)&Bs[(wc * 64 + ni * 16 + m15) * BK +
                                           (((kk * 4 + quad) ^ sw) * 8)];
#pragma unroll
            for (int mi = 0; mi < MI; mi++)
#pragma unroll
                for (int ni = 0; ni < 4; ni++)
                    acc[mi][ni] = __builtin_amdgcn_mfma_f32_16x16x32_bf16(
                        a[mi], bfr[ni], acc[mi][ni], 0, 0, 0);
        }
        __syncthreads();
    }

    if (VT_SEG2 && seg == 2) {
        // ---- V epilogue: LDS transpose, then coalesced Vt[bh][d][L] writes.
        // After the K-loop's final barrier, As/Bs are dead; overlay T[128][68].
        unsigned short* T = SMEM;
#pragma unroll
        for (int ni = 0; ni < 4; ni++) {
            int colc = wc * 64 + ni * 16 + m15;
            float bv = bias[n0 + colc];
#pragma unroll
            for (int mi = 0; mi < MI; mi++) {
#pragma unroll
                for (int r = 0; r < 4; r++) {
                    int rowc = wr * (MT / 2) + mi * 16 + quad * 4 + r;
                    T[colc * 68 + rowc] = f2bf((acc[mi][ni][r] + bv) * scl);
                }
            }
        }
        __syncthreads();
        const int b0 = m0 >> 11;       // batch of this m-tile (MT <= 2048)
        const int j0 = m0 & 2047;      // token base within batch
#pragma unroll
        for (int i = 0; i < MT / 16; i++) {  // 128 rows x MT/8 chunks / 256 thr
            int c = i * 256 + t;
            int rho = c >> 3, jc = c & 7;    // rho = local col (h,d), jc = j chunk
            v8s val = *(const v8s*)&T[rho * 68 + jc * 8];
            int colg = n0 + rho;
            int h = colg >> 6, d = colg & 63;
            *(v8s*)&((unsigned short*)Cp)[(((size_t)(b0 * 16 + h)) * 64 + d) * LLC +
                                          j0 + jc * 8] = val;
        }
        return;
    }

#pragma unroll
    for (int ni = 0; ni < 4; ni++) {
        int col = n0 + wc * 64 + ni * 16 + m15;
        float bv = bias[col];
#pragma unroll
        for (int mi = 0; mi < MI; mi++) {
#pragma unroll
            for (int r = 0; r < 4; r++) {
                int row = m0 + wr * (MT / 2) + mi * 16 + quad * 4 + r;
                float v = (acc[mi][ni][r] + bv) * scl;
                if (OUT_F32)
                    ((float*)Cp)[(size_t)row * N + col] = v;
                else
                    ((unsigned short*)Cp)[(size_t)row * N + col] = f2bf(v);
            }
        }
    }
}

// ---------------- MFMA flash attention: 8 waves x 16 q-rows (R13) ----------------
__global__ __launch_bounds__(512) void attn_mfma(const unsigned short* __restrict__ Qp,
                                                 const unsigned short* __restrict__ Kp,
                                                 const unsigned short* __restrict__ Vt,
                                                 unsigned short* __restrict__ X) {
    __shared__ __align__(16) unsigned short lds[8192 + 8192 + 128 * 72];
    unsigned short* Kb = lds;
    unsigned short* Vb = lds + 8192;
    unsigned short* PQ = lds + 16384;

    const int t = threadIdx.x;
    const int w = t >> 6, lane = t & 63;
    const int quad = lane >> 4, m15 = lane & 15;
    const int bh = blockIdx.y;
    const int b = bh >> 4, h = bh & 15;
    const int q0 = blockIdx.x * 128;
    const size_t hd = (size_t)h * 64;
    const int sw = m15 & 7;

    // Q staging: 128 rows x 8 chunks = 1024 chunks of 16B, 512 threads -> 2 iters
#pragma unroll
    for (int i = 0; i < 2; i++) {
        int chunk = i * 512 + t;
        int row = chunk >> 3, slot = chunk & 7;
        int j = slot ^ (row & 7);
        const unsigned short* g =
            Qp + ((size_t)(b * LLC + q0 + row)) * D_MODELC + hd + j * 8;
        __builtin_amdgcn_global_load_lds((const AS1 unsigned int*)g,
                                         (AS3 unsigned int*)(PQ + (i * 512 + w * 64) * 8),
                                         16, 0, 0);
    }
    {
        // K tile 0 (sigma row permutation) + V tile 0: 512 chunks each, 1 iter
        int row = t >> 3, slot = t & 7;
        int j = slot ^ (row & 7);
        int gr = 4 * (row & 15) + (row >> 4);  // sigma
        const unsigned short* gk =
            Kp + ((size_t)(b * LLC + 0 + gr)) * D_MODELC + hd + j * 8;
        __builtin_amdgcn_global_load_lds((const AS1 unsigned int*)gk,
                                         (AS3 unsigned int*)(Kb + (w * 64) * 8), 16, 0, 0);
        const unsigned short* gv = Vt + ((size_t)(bh * 64 + row)) * LLC + 0 + j * 8;
        __builtin_amdgcn_global_load_lds((const AS1 unsigned int*)gv,
                                         (AS3 unsigned int*)(Vb + (w * 64) * 8), 16, 0, 0);
    }
    __syncthreads();

    v8s qa[2];
#pragma unroll
    for (int kk = 0; kk < 2; kk++)
        qa[kk] = *(const v8s*)&PQ[(w * 16 + m15) * 64 + (((kk * 4 + quad) ^ sw) * 8)];
    __syncthreads();

    v8s ones;
#pragma unroll
    for (int u = 0; u < 8; u++) ones[u] = (short)0x3F80;  // bf16 1.0

    v4f O[4];
#pragma unroll
    for (int db = 0; db < 4; db++) O[db] = (v4f){0.f, 0.f, 0.f, 0.f};
    v4f lacc = (v4f){0.f, 0.f, 0.f, 0.f};

    for (int it = 0; it < 32; it++) {
        const int cur = it & 1;
        unsigned short* Kc = Kb + cur * 4096;
        unsigned short* Vc = Vb + cur * 4096;
        if (it < 31) {
            unsigned short* Kn = Kb + (cur ^ 1) * 4096;
            unsigned short* Vn = Vb + (cur ^ 1) * 4096;
            const int k0n = (it + 1) * 64;
            int row = t >> 3, slot = t & 7;
            int j = slot ^ (row & 7);
            int gr = 4 * (row & 15) + (row >> 4);
            const unsigned short* gk =
                Kp + ((size_t)(b * LLC + k0n + gr)) * D_MODELC + hd + j * 8;
            __builtin_amdgcn_global_load_lds((const AS1 unsigned int*)gk,
                                             (AS3 unsigned int*)(Kn + (w * 64) * 8), 16, 0, 0);
            const unsigned short* gv = Vt + ((size_t)(bh * 64 + row)) * LLC + k0n + j * 8;
            __builtin_amdgcn_global_load_lds((const AS1 unsigned int*)gv,
                                             (AS3 unsigned int*)(Vn + (w * 64) * 8), 16, 0, 0);
        }

        v4f S[4];
#pragma unroll
        for (int ns = 0; ns < 4; ns++) S[ns] = (v4f){0.f, 0.f, 0.f, 0.f};
#pragma unroll
        for (int kk = 0; kk < 2; kk++) {
#pragma unroll
            for (int ns = 0; ns < 4; ns++) {
                v8s kf = *(const v8s*)&Kc[(ns * 16 + m15) * 64 +
                                          (((kk * 4 + quad) ^ sw) * 8)];
                S[ns] = __builtin_amdgcn_mfma_f32_16x16x32_bf16(qa[kk], kf, S[ns], 0, 0, 0);
            }
        }

#pragma unroll
        for (int r = 0; r < 4; r++) {
            int prow = w * 16 + quad * 4 + r;
            float e0 = __builtin_amdgcn_exp2f(S[0][r]);
            float e1 = __builtin_amdgcn_exp2f(S[1][r]);
            float e2 = __builtin_amdgcn_exp2f(S[2][r]);
            float e3 = __builtin_amdgcn_exp2f(S[3][r]);
            uint2 pk;
            pk.x = pk2bf(e0, e1);
            pk.y = pk2bf(e2, e3);
            *(uint2*)&PQ[prow * 72 + 4 * m15] = pk;
        }

#pragma unroll
        for (int kk = 0; kk < 2; kk++) {
            v8s a0 = *(const v8s*)&PQ[(w * 16 + m15) * 72 + kk * 32 + quad * 8];
            lacc = __builtin_amdgcn_mfma_f32_16x16x32_bf16(a0, ones, lacc, 0, 0, 0);
#pragma unroll
            for (int db = 0; db < 4; db++) {
                v8s vf = *(const v8s*)&Vc[(db * 16 + m15) * 64 +
                                          (((kk * 4 + quad) ^ sw) * 8)];
                O[db] = __builtin_amdgcn_mfma_f32_16x16x32_bf16(a0, vf, O[db], 0, 0, 0);
            }
        }
        __syncthreads();
    }

#pragma unroll
    for (int r = 0; r < 4; r++) {
        float inv = 1.f / lacc[r];
        int row = q0 + w * 16 + quad * 4 + r;
#pragma unroll
        for (int db = 0; db < 4; db++) {
            X[((size_t)(b * LLC + row)) * D_MODELC + hd + db * 16 + m15] =
                f2bf(O[db][r] * inv);
        }
    }
}

extern "C" void kernel_launch(void* const* d_in, const int* in_sizes, int n_in,
                              void* d_out, int out_size, void* d_ws, size_t ws_size,
                              hipStream_t stream) {
    const float* q = (const float*)d_in[0];
    const float* k = (const float*)d_in[1];
    const float* v = (const float*)d_in[2];
    const float* w_q = (const float*)d_in[3];
    const float* b_q = (const float*)d_in[4];
    const float* w_k = (const float*)d_in[5];
    const float* b_k = (const float*)d_in[6];
    const float* w_v = (const float*)d_in[7];
    const float* b_v = (const float*)d_in[8];
    const float* w_o = (const float*)d_in[9];
    const float* b_o = (const float*)d_in[10];

    const size_t elems = (size_t)MMC * D_MODELC;  // 4M elems = 8MB bf16
    unsigned short* Qp = (unsigned short*)d_ws;   // X aliases Qp (see attn)
    unsigned short* Kp = Qp + elems;
    unsigned short* Vp = Kp + elems;              // unused (V writes go to Vt)
    unsigned short* Wt = Vp + elems;  // 4 x 1024x1024 bf16 = 8MB (q,k,v,o)
    unsigned short* X = Qp;
    unsigned short* Vt = (unsigned short*)d_out;  // scratch until final GEMM

    const float QSCALE = 0.125f * 1.44269504088896340736f;  // 1/sqrt(64)*log2(e)

    wtrans<<<dim3(16, 16, 4), 256, 0, stream>>>(w_q, w_k, w_v, w_o, Wt);

    // QKV: 3 segs x 64 m-tiles x 8 n-blocks = 1536 blocks, MT=64 BK=128.
    // seg==2 (V) writes directly into Vt layout (d_out scratch) via LDS
    // transpose epilogue.
    gemm_tile<64, 128, 3, true, false, true><<<1536, 256, 0, stream>>>(
        q, k, v, Wt, b_q, b_k, b_v, Qp, Kp, Vt, QSCALE, 1.f, 1.f);

    attn_mfma<<<dim3(LLC / 128, BBC * N_HEADSC), 512, 0, stream>>>(Qp, Kp, Vt, X);

    // final: 1 seg x 128 m-tiles x 8 n-blocks = 1024 blocks, MT=32 BK=128
    gemm_tile<32, 128, 1, false, true, false><<<1024, 256, 0, stream>>>(
        X, X, X, Wt + (size_t)3 * D_MODELC * D_MODELC, b_o, b_o, b_o,
        d_out, d_out, d_out, 1.f, 1.f, 1.f);
}

// Round 10
// 214.773 us; speedup vs baseline: 1.0843x; 1.0276x over previous
//
#include <hip/hip_runtime.h>
#include <hip/hip_bf16.h>

// MHA block: B=2, L=2048, D=1024, H=16, d_k=64.
// R19: two independent non-QKV levers (QKV = R18 byte-identical, best: 57.8us).
// (a) proj MT=32->64 (grid 512 = 2/CU fully resident, 32 MFMA/step, 48KB).
// (b) attn XCD-clustered decode: flat-512 grid, xcd=flat&7, bh=xcd*4+(s>>4),
//     qt=s&15 -- all 16 q-tiles of one bh land on one XCD so K/V staging hits
//     that XCD's L2 (~200cy) instead of HBM (~900cy). R13 measured 69.7MB
//     attn FETCH vs ~25MB ideal (K/V refetched by every XCD).
// gemm body (BK=128 R18), V-epilogue transpose (R17), wtrans unchanged.

#define D_MODELC 1024
#define N_HEADSC 16
#define D_KC 64
#define BBC 2
#define LLC 2048
#define MMC (BBC * LLC) /* 4096 */

typedef __attribute__((ext_vector_type(8))) short v8s;
typedef __attribute__((ext_vector_type(4))) float v4f;

__device__ __forceinline__ float bf2f(unsigned short u) {
    union { unsigned int i; float f; } x;
    x.i = ((unsigned int)u) << 16;
    return x.f;
}
__device__ __forceinline__ unsigned short f2bf(float f) {
    union { float f; unsigned int i; } x;
    x.f = f;
    unsigned int r = x.i + 0x7fffu + ((x.i >> 16) & 1u);  // RNE
    return (unsigned short)(r >> 16);
}
// packed f32x2 -> bf16x2 (v_cvt_pk_bf16_f32 on gfx950), low short = a
__device__ __forceinline__ unsigned int pk2bf(float a, float b) {
    __hip_bfloat162 h = __float22bfloat162_rn(make_float2(a, b));
    return *(unsigned int*)&h;
}

#define AS1 __attribute__((address_space(1)))
#define AS3 __attribute__((address_space(3)))

// ---------------- weight transpose+convert: Wt[z][n][k] = W_z[k][n] ----------------
__global__ __launch_bounds__(256) void wtrans(const float* __restrict__ w0,
                                              const float* __restrict__ w1,
                                              const float* __restrict__ w2,
                                              const float* __restrict__ w3,
                                              unsigned short* __restrict__ out) {
    __shared__ unsigned short T[64][65];
    const int z = blockIdx.z;
    const float* W = z == 0 ? w0 : (z == 1 ? w1 : (z == 2 ? w2 : w3));
    unsigned short* O = out + (size_t)z * D_MODELC * D_MODELC;
    const int k0 = blockIdx.y * 64, n0 = blockIdx.x * 64;
    const int c = threadIdx.x & 63, r4 = threadIdx.x >> 6;
#pragma unroll
    for (int i = 0; i < 16; i++) {
        int r = i * 4 + r4;
        T[r][c] = f2bf(W[(size_t)(k0 + r) * D_MODELC + n0 + c]);
    }
    __syncthreads();
#pragma unroll
    for (int i = 0; i < 16; i++) {
        int r = i * 4 + r4;
        O[(size_t)(n0 + r) * D_MODELC + k0 + c] = T[c][r];
    }
}

// ---------------- GEMM, 2-barrier K-loop, BK-templated, XCD-grouped ----------------
// LDS rows are BK shorts; chunk slot s of row r lives at global chunk
// j = (s & ~7) | ((s&7) ^ (r&7)) (swizzle on the GLOBAL address for async
// staging / ds_write slot). Frag reads use chunk ^ sw with sw = m15&7 (low-3
// bits only, so the identity holds for chunk >= 8 too).
// VT_SEG2: seg==2 routes its output through an LDS transpose and writes
// Vt[bh][d][L] with 16B coalesced stores -- replaces the vtrans kernel.
template <int MT, int BK, int SEGS, bool A_F32, bool OUT_F32, bool VT_SEG2>
__global__ __launch_bounds__(256) void gemm_tile(
    const void* __restrict__ A0, const void* __restrict__ A1, const void* __restrict__ A2,
    const unsigned short* __restrict__ Wt,
    const float* __restrict__ bias0, const float* __restrict__ bias1,
    const float* __restrict__ bias2,
    void* __restrict__ C0, void* __restrict__ C1, void* __restrict__ C2,
    float scale0, float scale1, float scale2) {
    const int K = D_MODELC, N = D_MODELC;
    constexpr int MI = MT / 32;          // MFMA row-tiles per wave
    constexpr int MB = MMC / MT;         // m-tiles
    constexpr int PER = SEGS * MB / 8;   // groups per XCD
    constexpr int CPR = BK / 8;          // 16B chunks per LDS row
    constexpr int BIT = 128 * CPR / 256; // B staging iters per K-step
    constexpr int AIT = MT * CPR / 256;  // A staging iters per K-step
    // As/Bs share one allocation; the V-epilogue transpose tile T (128x68
    // shorts) overlays it after the K-loop (both dead by then).
    __shared__ __align__(16) unsigned short SMEM[MT * BK + 128 * BK];
    unsigned short* As = SMEM;
    unsigned short* Bs = SMEM + MT * BK;

    const int t = threadIdx.x;
    const int w = t >> 6, lane = t & 63;
    const int quad = lane >> 4, m15 = lane & 15;
    const int wr = w >> 1, wc = w & 1;
    const int sw = m15 & 7;

    // XCD-grouped decode (8 n-blocks of one (seg,mb) share blockIdx%8)
    const int flat = blockIdx.x;
    const int xcd = flat & 7;
    const int slot0 = flat >> 3;
    const int group = xcd * PER + (slot0 >> 3);
    const int nb = slot0 & 7;
    const int seg = group / MB;
    const int mb = group % MB;
    const int n0 = nb * 128;
    const int m0 = mb * MT;

    const void* Ap = seg == 0 ? A0 : (seg == 1 ? A1 : A2);
    const unsigned short* Wp = Wt + (size_t)seg * D_MODELC * D_MODELC;
    const float* bias = seg == 0 ? bias0 : (seg == 1 ? bias1 : bias2);
    void* Cp = seg == 0 ? C0 : (seg == 1 ? C1 : C2);
    const float scl = seg == 0 ? scale0 : (seg == 1 ? scale1 : scale2);

    v4f acc[MI][4];
#pragma unroll
    for (int mi = 0; mi < MI; mi++)
#pragma unroll
        for (int ni = 0; ni < 4; ni++) acc[mi][ni] = (v4f){0.f, 0.f, 0.f, 0.f};

    for (int k0 = 0; k0 < K; k0 += BK) {
        // B staging: 128 rows x CPR chunks, async direct-to-LDS.
        // LDS linear (wave base + lane*16), global chunk j = swizzled slot.
#pragma unroll
        for (int i = 0; i < BIT; i++) {
            int c = i * 256 + t;
            int row = c / CPR, slot = c % CPR;
            int j = (slot & ~7) | ((slot & 7) ^ (row & 7));
            const unsigned short* g = Wp + (size_t)(n0 + row) * K + k0 + j * 8;
            __builtin_amdgcn_global_load_lds(
                (const AS1 unsigned int*)g,
                (AS3 unsigned int*)(Bs + (size_t)c * 8), 16, 0, 0);
        }
        if (A_F32) {
            // fp32 A: vector loads + packed convert + swizzled ds_write
#pragma unroll
            for (int i = 0; i < AIT; i++) {
                int c = i * 256 + t;
                int row = c / CPR, slot = c % CPR;
                int j = (slot & ~7) | ((slot & 7) ^ (row & 7));
                const float* src = (const float*)Ap + (size_t)(m0 + row) * K + k0 + j * 8;
                float4 f0 = ((const float4*)src)[0];
                float4 f1 = ((const float4*)src)[1];
                uint4 pk;
                pk.x = pk2bf(f0.x, f0.y);
                pk.y = pk2bf(f0.z, f0.w);
                pk.z = pk2bf(f1.x, f1.y);
                pk.w = pk2bf(f1.z, f1.w);
                *(uint4*)&As[(size_t)c * 8] = pk;
            }
        } else {
#pragma unroll
            for (int i = 0; i < AIT; i++) {
                int c = i * 256 + t;
                int row = c / CPR, slot = c % CPR;
                int j = (slot & ~7) | ((slot & 7) ^ (row & 7));
                const unsigned short* g =
                    (const unsigned short*)Ap + (size_t)(m0 + row) * K + k0 + j * 8;
                __builtin_amdgcn_global_load_lds(
                    (const AS1 unsigned int*)g,
                    (AS3 unsigned int*)(As + (size_t)c * 8), 16, 0, 0);
            }
        }
        __syncthreads();

#pragma unroll
        for (int kk = 0; kk < BK / 32; kk++) {
            v8s a[MI], bfr[4];
#pragma unroll
            for (int mi = 0; mi < MI; mi++)
                a[mi] = *(const v8s*)&As[(wr * (MT / 2) + mi * 16 + m15) * BK +
                                         (((kk * 4 + quad) ^ sw) * 8)];
#pragma unroll
            for (int ni = 0; ni < 4; ni++)
                bfr[ni] = *(const v8s*)&Bs[(wc * 64 + ni * 16 + m15) * BK +
                                           (((kk * 4 + quad) ^ sw) * 8)];
#pragma unroll
            for (int mi = 0; mi < MI; mi++)
#pragma unroll
                for (int ni = 0; ni < 4; ni++)
                    acc[mi][ni] = __builtin_amdgcn_mfma_f32_16x16x32_bf16(
                        a[mi], bfr[ni], acc[mi][ni], 0, 0, 0);
        }
        __syncthreads();
    }

    if (VT_SEG2 && seg == 2) {
        // ---- V epilogue: LDS transpose, then coalesced Vt[bh][d][L] writes.
        // After the K-loop's final barrier, As/Bs are dead; overlay T[128][68].
        unsigned short* T = SMEM;
#pragma unroll
        for (int ni = 0; ni < 4; ni++) {
            int colc = wc * 64 + ni * 16 + m15;
            float bv = bias[n0 + colc];
#pragma unroll
            for (int mi = 0; mi < MI; mi++) {
#pragma unroll
                for (int r = 0; r < 4; r++) {
                    int rowc = wr * (MT / 2) + mi * 16 + quad * 4 + r;
                    T[colc * 68 + rowc] = f2bf((acc[mi][ni][r] + bv) * scl);
                }
            }
        }
        __syncthreads();
        const int b0 = m0 >> 11;       // batch of this m-tile (MT <= 2048)
        const int j0 = m0 & 2047;      // token base within batch
#pragma unroll
        for (int i = 0; i < MT / 16; i++) {  // 128 rows x MT/8 chunks / 256 thr
            int c = i * 256 + t;
            int rho = c >> 3, jc = c & 7;    // rho = local col (h,d), jc = j chunk
            v8s val = *(const v8s*)&T[rho * 68 + jc * 8];
            int colg = n0 + rho;
            int h = colg >> 6, d = colg & 63;
            *(v8s*)&((unsigned short*)Cp)[(((size_t)(b0 * 16 + h)) * 64 + d) * LLC +
                                          j0 + jc * 8] = val;
        }
        return;
    }

#pragma unroll
    for (int ni = 0; ni < 4; ni++) {
        int col = n0 + wc * 64 + ni * 16 + m15;
        float bv = bias[col];
#pragma unroll
        for (int mi = 0; mi < MI; mi++) {
#pragma unroll
            for (int r = 0; r < 4; r++) {
                int row = m0 + wr * (MT / 2) + mi * 16 + quad * 4 + r;
                float v = (acc[mi][ni][r] + bv) * scl;
                if (OUT_F32)
                    ((float*)Cp)[(size_t)row * N + col] = v;
                else
                    ((unsigned short*)Cp)[(size_t)row * N + col] = f2bf(v);
            }
        }
    }
}

// ---------------- MFMA flash attention: 8 waves x 16 q-rows, XCD-clustered ----------------
// Flat 512-block grid. xcd = flat&7; s = flat>>3; bh = xcd*4 + (s>>4);
// q-tile = s&15. All 16 q-tiles of one bh (512KB K/V) stay on one XCD's L2.
__global__ __launch_bounds__(512) void attn_mfma(const unsigned short* __restrict__ Qp,
                                                 const unsigned short* __restrict__ Kp,
                                                 const unsigned short* __restrict__ Vt,
                                                 unsigned short* __restrict__ X) {
    __shared__ __align__(16) unsigned short lds[8192 + 8192 + 128 * 72];
    unsigned short* Kb = lds;
    unsigned short* Vb = lds + 8192;
    unsigned short* PQ = lds + 16384;

    const int t = threadIdx.x;
    const int w = t >> 6, lane = t & 63;
    const int quad = lane >> 4, m15 = lane & 15;
    const int flat = blockIdx.x;
    const int xcd = flat & 7;
    const int s = flat >> 3;
    const int bh = xcd * 4 + (s >> 4);
    const int b = bh >> 4, h = bh & 15;
    const int q0 = (s & 15) * 128;
    const size_t hd = (size_t)h * 64;
    const int sw = m15 & 7;

    // Q staging: 128 rows x 8 chunks = 1024 chunks of 16B, 512 threads -> 2 iters
#pragma unroll
    for (int i = 0; i < 2; i++) {
        int chunk = i * 512 + t;
        int row = chunk >> 3, slot = chunk & 7;
        int j = slot ^ (row & 7);
        const unsigned short* g =
            Qp + ((size_t)(b * LLC + q0 + row)) * D_MODELC + hd + j * 8;
        __builtin_amdgcn_global_load_lds((const AS1 unsigned int*)g,
                                         (AS3 unsigned int*)(PQ + (i * 512 + w * 64) * 8),
                                         16, 0, 0);
    }
    {
        // K tile 0 (sigma row permutation) + V tile 0: 512 chunks each, 1 iter
        int row = t >> 3, slot = t & 7;
        int j = slot ^ (row & 7);
        int gr = 4 * (row & 15) + (row >> 4);  // sigma
        const unsigned short* gk =
            Kp + ((size_t)(b * LLC + 0 + gr)) * D_MODELC + hd + j * 8;
        __builtin_amdgcn_global_load_lds((const AS1 unsigned int*)gk,
                                         (AS3 unsigned int*)(Kb + (w * 64) * 8), 16, 0, 0);
        const unsigned short* gv = Vt + ((size_t)(bh * 64 + row)) * LLC + 0 + j * 8;
        __builtin_amdgcn_global_load_lds((const AS1 unsigned int*)gv,
                                         (AS3 unsigned int*)(Vb + (w * 64) * 8), 16, 0, 0);
    }
    __syncthreads();

    v8s qa[2];
#pragma unroll
    for (int kk = 0; kk < 2; kk++)
        qa[kk] = *(const v8s*)&PQ[(w * 16 + m15) * 64 + (((kk * 4 + quad) ^ sw) * 8)];
    __syncthreads();

    v8s ones;
#pragma unroll
    for (int u = 0; u < 8; u++) ones[u] = (short)0x3F80;  // bf16 1.0

    v4f O[4];
#pragma unroll
    for (int db = 0; db < 4; db++) O[db] = (v4f){0.f, 0.f, 0.f, 0.f};
    v4f lacc = (v4f){0.f, 0.f, 0.f, 0.f};

    for (int it = 0; it < 32; it++) {
        const int cur = it & 1;
        unsigned short* Kc = Kb + cur * 4096;
        unsigned short* Vc = Vb + cur * 4096;
        if (it < 31) {
            unsigned short* Kn = Kb + (cur ^ 1) * 4096;
            unsigned short* Vn = Vb + (cur ^ 1) * 4096;
            const int k0n = (it + 1) * 64;
            int row = t >> 3, slot = t & 7;
            int j = slot ^ (row & 7);
            int gr = 4 * (row & 15) + (row >> 4);
            const unsigned short* gk =
                Kp + ((size_t)(b * LLC + k0n + gr)) * D_MODELC + hd + j * 8;
            __builtin_amdgcn_global_load_lds((const AS1 unsigned int*)gk,
                                             (AS3 unsigned int*)(Kn + (w * 64) * 8), 16, 0, 0);
            const unsigned short* gv = Vt + ((size_t)(bh * 64 + row)) * LLC + k0n + j * 8;
            __builtin_amdgcn_global_load_lds((const AS1 unsigned int*)gv,
                                             (AS3 unsigned int*)(Vn + (w * 64) * 8), 16, 0, 0);
        }

        v4f S[4];
#pragma unroll
        for (int ns = 0; ns < 4; ns++) S[ns] = (v4f){0.f, 0.f, 0.f, 0.f};
#pragma unroll
        for (int kk = 0; kk < 2; kk++) {
#pragma unroll
            for (int ns = 0; ns < 4; ns++) {
                v8s kf = *(const v8s*)&Kc[(ns * 16 + m15) * 64 +
                                          (((kk * 4 + quad) ^ sw) * 8)];
                S[ns] = __builtin_amdgcn_mfma_f32_16x16x32_bf16(qa[kk], kf, S[ns], 0, 0, 0);
            }
        }

#pragma unroll
        for (int r = 0; r < 4; r++) {
            int prow = w * 16 + quad * 4 + r;
            float e0 = __builtin_amdgcn_exp2f(S[0][r]);
            float e1 = __builtin_amdgcn_exp2f(S[1][r]);
            float e2 = __builtin_amdgcn_exp2f(S[2][r]);
            float e3 = __builtin_amdgcn_exp2f(S[3][r]);
            uint2 pk;
            pk.x = pk2bf(e0, e1);
            pk.y = pk2bf(e2, e3);
            *(uint2*)&PQ[prow * 72 + 4 * m15] = pk;
        }

#pragma unroll
        for (int kk = 0; kk < 2; kk++) {
            v8s a0 = *(const v8s*)&PQ[(w * 16 + m15) * 72 + kk * 32 + quad * 8];
            lacc = __builtin_amdgcn_mfma_f32_16x16x32_bf16(a0, ones, lacc, 0, 0, 0);
#pragma unroll
            for (int db = 0; db < 4; db++) {
                v8s vf = *(const v8s*)&Vc[(db * 16 + m15) * 64 +
                                          (((kk * 4 + quad) ^ sw) * 8)];
                O[db] = __builtin_amdgcn_mfma_f32_16x16x32_bf16(a0, vf, O[db], 0, 0, 0);
            }
        }
        __syncthreads();
    }

#pragma unroll
    for (int r = 0; r < 4; r++) {
        float inv = 1.f / lacc[r];
        int row = q0 + w * 16 + quad * 4 + r;
#pragma unroll
        for (int db = 0; db < 4; db++) {
            X[((size_t)(b * LLC + row)) * D_MODELC + hd + db * 16 + m15] =
                f2bf(O[db][r] * inv);
        }
    }
}

extern "C" void kernel_launch(void* const* d_in, const int* in_sizes, int n_in,
                              void* d_out, int out_size, void* d_ws, size_t ws_size,
                              hipStream_t stream) {
    const float* q = (const float*)d_in[0];
    const float* k = (const float*)d_in[1];
    const float* v = (const float*)d_in[2];
    const float* w_q = (const float*)d_in[3];
    const float* b_q = (const float*)d_in[4];
    const float* w_k = (const float*)d_in[5];
    const float* b_k = (const float*)d_in[6];
    const float* w_v = (const float*)d_in[7];
    const float* b_v = (const float*)d_in[8];
    const float* w_o = (const float*)d_in[9];
    const float* b_o = (const float*)d_in[10];

    const size_t elems = (size_t)MMC * D_MODELC;  // 4M elems = 8MB bf16
    unsigned short* Qp = (unsigned short*)d_ws;   // X aliases Qp (see attn)
    unsigned short* Kp = Qp + elems;
    unsigned short* Vp = Kp + elems;              // unused (V writes go to Vt)
    unsigned short* Wt = Vp + elems;  // 4 x 1024x1024 bf16 = 8MB (q,k,v,o)
    unsigned short* X = Qp;
    unsigned short* Vt = (unsigned short*)d_out;  // scratch until final GEMM

    const float QSCALE = 0.125f * 1.44269504088896340736f;  // 1/sqrt(64)*log2(e)

    wtrans<<<dim3(16, 16, 4), 256, 0, stream>>>(w_q, w_k, w_v, w_o, Wt);

    // QKV: 3 segs x 64 m-tiles x 8 n-blocks = 1536 blocks, MT=64 BK=128.
    // seg==2 (V) writes directly into Vt layout (d_out scratch) via LDS
    // transpose epilogue.
    gemm_tile<64, 128, 3, true, false, true><<<1536, 256, 0, stream>>>(
        q, k, v, Wt, b_q, b_k, b_v, Qp, Kp, Vt, QSCALE, 1.f, 1.f);

    // attn: flat 512 blocks, XCD-clustered (4 bh per XCD, 16 q-tiles each)
    attn_mfma<<<512, 512, 0, stream>>>(Qp, Kp, Vt, X);

    // final: 1 seg x 64 m-tiles x 8 n-blocks = 512 blocks, MT=64 BK=128
    gemm_tile<64, 128, 1, false, true, false><<<512, 256, 0, stream>>>(
        X, X, X, Wt + (size_t)3 * D_MODELC * D_MODELC, b_o, b_o, b_o,
        d_out, d_out, d_out, 1.f, 1.f, 1.f);
}

// Round 11
// 212.180 us; speedup vs baseline: 1.0976x; 1.0122x over previous
//
#include <hip/hip_runtime.h>
#include <hip/hip_bf16.h>

// MHA block: B=2, L=2048, D=1024, H=16, d_k=64.
// R21: two small levers on the R19 winner (214.8us).
// (a) QKV A_F32 staging issue-order fix: fp32 A loads issue FIRST into regs
//     (af[AIT][2], fully unrolled), THEN B's async global_load_lds, THEN
//     cvt+ds_write. vmcnt counts in-order vs oldest: previously "wait for A"
//     (newest) meant draining all 8 older B loads every K-step. Now cvt waits
//     vmcnt(8) with B in flight, and A's ~900cy HBM latency starts earliest.
// (b) attn: T5 s_setprio(1/0) around QK and PV MFMA clusters (m191: +4-7%
//     on attn-style kernels; 2 independent blocks/CU -> role diversity).
// Everything else byte-identical to R19 (QKV MT=64 BK=128, proj MT=64,
// V-epilogue LDS transpose, XCD-clustered attn decode, wtrans).

#define D_MODELC 1024
#define N_HEADSC 16
#define D_KC 64
#define BBC 2
#define LLC 2048
#define MMC (BBC * LLC) /* 4096 */

typedef __attribute__((ext_vector_type(8))) short v8s;
typedef __attribute__((ext_vector_type(4))) float v4f;

__device__ __forceinline__ float bf2f(unsigned short u) {
    union { unsigned int i; float f; } x;
    x.i = ((unsigned int)u) << 16;
    return x.f;
}
__device__ __forceinline__ unsigned short f2bf(float f) {
    union { float f; unsigned int i; } x;
    x.f = f;
    unsigned int r = x.i + 0x7fffu + ((x.i >> 16) & 1u);  // RNE
    return (unsigned short)(r >> 16);
}
// packed f32x2 -> bf16x2 (v_cvt_pk_bf16_f32 on gfx950), low short = a
__device__ __forceinline__ unsigned int pk2bf(float a, float b) {
    __hip_bfloat162 h = __float22bfloat162_rn(make_float2(a, b));
    return *(unsigned int*)&h;
}

#define AS1 __attribute__((address_space(1)))
#define AS3 __attribute__((address_space(3)))

// ---------------- weight transpose+convert: Wt[z][n][k] = W_z[k][n] ----------------
__global__ __launch_bounds__(256) void wtrans(const float* __restrict__ w0,
                                              const float* __restrict__ w1,
                                              const float* __restrict__ w2,
                                              const float* __restrict__ w3,
                                              unsigned short* __restrict__ out) {
    __shared__ unsigned short T[64][65];
    const int z = blockIdx.z;
    const float* W = z == 0 ? w0 : (z == 1 ? w1 : (z == 2 ? w2 : w3));
    unsigned short* O = out + (size_t)z * D_MODELC * D_MODELC;
    const int k0 = blockIdx.y * 64, n0 = blockIdx.x * 64;
    const int c = threadIdx.x & 63, r4 = threadIdx.x >> 6;
#pragma unroll
    for (int i = 0; i < 16; i++) {
        int r = i * 4 + r4;
        T[r][c] = f2bf(W[(size_t)(k0 + r) * D_MODELC + n0 + c]);
    }
    __syncthreads();
#pragma unroll
    for (int i = 0; i < 16; i++) {
        int r = i * 4 + r4;
        O[(size_t)(n0 + r) * D_MODELC + k0 + c] = T[c][r];
    }
}

// ---------------- GEMM, 2-barrier K-loop, BK-templated, XCD-grouped ----------------
// LDS rows are BK shorts; chunk slot s of row r lives at global chunk
// j = (s & ~7) | ((s&7) ^ (r&7)) (swizzle on the GLOBAL address for async
// staging / ds_write slot). Frag reads use chunk ^ sw with sw = m15&7.
// A_F32 staging order: A fp32 loads issue FIRST (regs), then B async loads,
// then cvt+ds_write -- cvt waits only on A (vmcnt(8)), B stays in flight.
// VT_SEG2: seg==2 routes its output through an LDS transpose and writes
// Vt[bh][d][L] with 16B coalesced stores -- replaces the vtrans kernel.
template <int MT, int BK, int SEGS, bool A_F32, bool OUT_F32, bool VT_SEG2>
__global__ __launch_bounds__(256) void gemm_tile(
    const void* __restrict__ A0, const void* __restrict__ A1, const void* __restrict__ A2,
    const unsigned short* __restrict__ Wt,
    const float* __restrict__ bias0, const float* __restrict__ bias1,
    const float* __restrict__ bias2,
    void* __restrict__ C0, void* __restrict__ C1, void* __restrict__ C2,
    float scale0, float scale1, float scale2) {
    const int K = D_MODELC, N = D_MODELC;
    constexpr int MI = MT / 32;          // MFMA row-tiles per wave
    constexpr int MB = MMC / MT;         // m-tiles
    constexpr int PER = SEGS * MB / 8;   // groups per XCD
    constexpr int CPR = BK / 8;          // 16B chunks per LDS row
    constexpr int BIT = 128 * CPR / 256; // B staging iters per K-step
    constexpr int AIT = MT * CPR / 256;  // A staging iters per K-step
    // As/Bs share one allocation; the V-epilogue transpose tile T (128x68
    // shorts) overlays it after the K-loop (both dead by then).
    __shared__ __align__(16) unsigned short SMEM[MT * BK + 128 * BK];
    unsigned short* As = SMEM;
    unsigned short* Bs = SMEM + MT * BK;

    const int t = threadIdx.x;
    const int w = t >> 6, lane = t & 63;
    const int quad = lane >> 4, m15 = lane & 15;
    const int wr = w >> 1, wc = w & 1;
    const int sw = m15 & 7;

    // XCD-grouped decode (8 n-blocks of one (seg,mb) share blockIdx%8)
    const int flat = blockIdx.x;
    const int xcd = flat & 7;
    const int slot0 = flat >> 3;
    const int group = xcd * PER + (slot0 >> 3);
    const int nb = slot0 & 7;
    const int seg = group / MB;
    const int mb = group % MB;
    const int n0 = nb * 128;
    const int m0 = mb * MT;

    const void* Ap = seg == 0 ? A0 : (seg == 1 ? A1 : A2);
    const unsigned short* Wp = Wt + (size_t)seg * D_MODELC * D_MODELC;
    const float* bias = seg == 0 ? bias0 : (seg == 1 ? bias1 : bias2);
    void* Cp = seg == 0 ? C0 : (seg == 1 ? C1 : C2);
    const float scl = seg == 0 ? scale0 : (seg == 1 ? scale1 : scale2);

    v4f acc[MI][4];
#pragma unroll
    for (int mi = 0; mi < MI; mi++)
#pragma unroll
        for (int ni = 0; ni < 4; ni++) acc[mi][ni] = (v4f){0.f, 0.f, 0.f, 0.f};

    float4 af[AIT > 0 ? AIT : 1][2];  // in-flight fp32 A chunks (A_F32 only)

    for (int k0 = 0; k0 < K; k0 += BK) {
        if (A_F32) {
            // (1) issue ALL fp32 A loads first -- their HBM latency starts now
#pragma unroll
            for (int i = 0; i < AIT; i++) {
                int c = i * 256 + t;
                int row = c / CPR, slot = c % CPR;
                int j = (slot & ~7) | ((slot & 7) ^ (row & 7));
                const float* src = (const float*)Ap + (size_t)(m0 + row) * K + k0 + j * 8;
                af[i][0] = ((const float4*)src)[0];
                af[i][1] = ((const float4*)src)[1];
            }
        }
        // (2) B staging: async direct-to-LDS, queued behind A (B is L2-warm)
#pragma unroll
        for (int i = 0; i < BIT; i++) {
            int c = i * 256 + t;
            int row = c / CPR, slot = c % CPR;
            int j = (slot & ~7) | ((slot & 7) ^ (row & 7));
            const unsigned short* g = Wp + (size_t)(n0 + row) * K + k0 + j * 8;
            __builtin_amdgcn_global_load_lds(
                (const AS1 unsigned int*)g,
                (AS3 unsigned int*)(Bs + (size_t)c * 8), 16, 0, 0);
        }
        if (A_F32) {
            // (3) convert + swizzled ds_write; waits only on A's loads
#pragma unroll
            for (int i = 0; i < AIT; i++) {
                int c = i * 256 + t;
                uint4 pk;
                pk.x = pk2bf(af[i][0].x, af[i][0].y);
                pk.y = pk2bf(af[i][0].z, af[i][0].w);
                pk.z = pk2bf(af[i][1].x, af[i][1].y);
                pk.w = pk2bf(af[i][1].z, af[i][1].w);
                *(uint4*)&As[(size_t)c * 8] = pk;
            }
        } else {
#pragma unroll
            for (int i = 0; i < AIT; i++) {
                int c = i * 256 + t;
                int row = c / CPR, slot = c % CPR;
                int j = (slot & ~7) | ((slot & 7) ^ (row & 7));
                const unsigned short* g =
                    (const unsigned short*)Ap + (size_t)(m0 + row) * K + k0 + j * 8;
                __builtin_amdgcn_global_load_lds(
                    (const AS1 unsigned int*)g,
                    (AS3 unsigned int*)(As + (size_t)c * 8), 16, 0, 0);
            }
        }
        __syncthreads();

#pragma unroll
        for (int kk = 0; kk < BK / 32; kk++) {
            v8s a[MI], bfr[4];
#pragma unroll
            for (int mi = 0; mi < MI; mi++)
                a[mi] = *(const v8s*)&As[(wr * (MT / 2) + mi * 16 + m15) * BK +
                                         (((kk * 4 + quad) ^ sw) * 8)];
#pragma unroll
            for (int ni = 0; ni < 4; ni++)
                bfr[ni] = *(const v8s*)&Bs[(wc * 64 + ni * 16 + m15) * BK +
                                           (((kk * 4 + quad) ^ sw) * 8)];
#pragma unroll
            for (int mi = 0; mi < MI; mi++)
#pragma unroll
                for (int ni = 0; ni < 4; ni++)
                    acc[mi][ni] = __builtin_amdgcn_mfma_f32_16x16x32_bf16(
                        a[mi], bfr[ni], acc[mi][ni], 0, 0, 0);
        }
        __syncthreads();
    }

    if (VT_SEG2 && seg == 2) {
        // ---- V epilogue: LDS transpose, then coalesced Vt[bh][d][L] writes.
        // After the K-loop's final barrier, As/Bs are dead; overlay T[128][68].
        unsigned short* T = SMEM;
#pragma unroll
        for (int ni = 0; ni < 4; ni++) {
            int colc = wc * 64 + ni * 16 + m15;
            float bv = bias[n0 + colc];
#pragma unroll
            for (int mi = 0; mi < MI; mi++) {
#pragma unroll
                for (int r = 0; r < 4; r++) {
                    int rowc = wr * (MT / 2) + mi * 16 + quad * 4 + r;
                    T[colc * 68 + rowc] = f2bf((acc[mi][ni][r] + bv) * scl);
                }
            }
        }
        __syncthreads();
        const int b0 = m0 >> 11;       // batch of this m-tile (MT <= 2048)
        const int j0 = m0 & 2047;      // token base within batch
#pragma unroll
        for (int i = 0; i < MT / 16; i++) {  // 128 rows x MT/8 chunks / 256 thr
            int c = i * 256 + t;
            int rho = c >> 3, jc = c & 7;    // rho = local col (h,d), jc = j chunk
            v8s val = *(const v8s*)&T[rho * 68 + jc * 8];
            int colg = n0 + rho;
            int h = colg >> 6, d = colg & 63;
            *(v8s*)&((unsigned short*)Cp)[(((size_t)(b0 * 16 + h)) * 64 + d) * LLC +
                                          j0 + jc * 8] = val;
        }
        return;
    }

#pragma unroll
    for (int ni = 0; ni < 4; ni++) {
        int col = n0 + wc * 64 + ni * 16 + m15;
        float bv = bias[col];
#pragma unroll
        for (int mi = 0; mi < MI; mi++) {
#pragma unroll
            for (int r = 0; r < 4; r++) {
                int row = m0 + wr * (MT / 2) + mi * 16 + quad * 4 + r;
                float v = (acc[mi][ni][r] + bv) * scl;
                if (OUT_F32)
                    ((float*)Cp)[(size_t)row * N + col] = v;
                else
                    ((unsigned short*)Cp)[(size_t)row * N + col] = f2bf(v);
            }
        }
    }
}

// ---------------- MFMA flash attention: 8 waves x 16 q-rows, XCD-clustered ----------------
// Flat 512-block grid. xcd = flat&7; s = flat>>3; bh = xcd*4 + (s>>4);
// q-tile = s&15. All 16 q-tiles of one bh (512KB K/V) stay on one XCD's L2.
// T5: s_setprio(1) around the QK and PV MFMA clusters.
__global__ __launch_bounds__(512) void attn_mfma(const unsigned short* __restrict__ Qp,
                                                 const unsigned short* __restrict__ Kp,
                                                 const unsigned short* __restrict__ Vt,
                                                 unsigned short* __restrict__ X) {
    __shared__ __align__(16) unsigned short lds[8192 + 8192 + 128 * 72];
    unsigned short* Kb = lds;
    unsigned short* Vb = lds + 8192;
    unsigned short* PQ = lds + 16384;

    const int t = threadIdx.x;
    const int w = t >> 6, lane = t & 63;
    const int quad = lane >> 4, m15 = lane & 15;
    const int flat = blockIdx.x;
    const int xcd = flat & 7;
    const int s = flat >> 3;
    const int bh = xcd * 4 + (s >> 4);
    const int b = bh >> 4, h = bh & 15;
    const int q0 = (s & 15) * 128;
    const size_t hd = (size_t)h * 64;
    const int sw = m15 & 7;

    // Q staging: 128 rows x 8 chunks = 1024 chunks of 16B, 512 threads -> 2 iters
#pragma unroll
    for (int i = 0; i < 2; i++) {
        int chunk = i * 512 + t;
        int row = chunk >> 3, slot = chunk & 7;
        int j = slot ^ (row & 7);
        const unsigned short* g =
            Qp + ((size_t)(b * LLC + q0 + row)) * D_MODELC + hd + j * 8;
        __builtin_amdgcn_global_load_lds((const AS1 unsigned int*)g,
                                         (AS3 unsigned int*)(PQ + (i * 512 + w * 64) * 8),
                                         16, 0, 0);
    }
    {
        // K tile 0 (sigma row permutation) + V tile 0: 512 chunks each, 1 iter
        int row = t >> 3, slot = t & 7;
        int j = slot ^ (row & 7);
        int gr = 4 * (row & 15) + (row >> 4);  // sigma
        const unsigned short* gk =
            Kp + ((size_t)(b * LLC + 0 + gr)) * D_MODELC + hd + j * 8;
        __builtin_amdgcn_global_load_lds((const AS1 unsigned int*)gk,
                                         (AS3 unsigned int*)(Kb + (w * 64) * 8), 16, 0, 0);
        const unsigned short* gv = Vt + ((size_t)(bh * 64 + row)) * LLC + 0 + j * 8;
        __builtin_amdgcn_global_load_lds((const AS1 unsigned int*)gv,
                                         (AS3 unsigned int*)(Vb + (w * 64) * 8), 16, 0, 0);
    }
    __syncthreads();

    v8s qa[2];
#pragma unroll
    for (int kk = 0; kk < 2; kk++)
        qa[kk] = *(const v8s*)&PQ[(w * 16 + m15) * 64 + (((kk * 4 + quad) ^ sw) * 8)];
    __syncthreads();

    v8s ones;
#pragma unroll
    for (int u = 0; u < 8; u++) ones[u] = (short)0x3F80;  // bf16 1.0

    v4f O[4];
#pragma unroll
    for (int db = 0; db < 4; db++) O[db] = (v4f){0.f, 0.f, 0.f, 0.f};
    v4f lacc = (v4f){0.f, 0.f, 0.f, 0.f};

    for (int it = 0; it < 32; it++) {
        const int cur = it & 1;
        unsigned short* Kc = Kb + cur * 4096;
        unsigned short* Vc = Vb + cur * 4096;
        if (it < 31) {
            unsigned short* Kn = Kb + (cur ^ 1) * 4096;
            unsigned short* Vn = Vb + (cur ^ 1) * 4096;
            const int k0n = (it + 1) * 64;
            int row = t >> 3, slot = t & 7;
            int j = slot ^ (row & 7);
            int gr = 4 * (row & 15) + (row >> 4);
            const unsigned short* gk =
                Kp + ((size_t)(b * LLC + k0n + gr)) * D_MODELC + hd + j * 8;
            __builtin_amdgcn_global_load_lds((const AS1 unsigned int*)gk,
                                             (AS3 unsigned int*)(Kn + (w * 64) * 8), 16, 0, 0);
            const unsigned short* gv = Vt + ((size_t)(bh * 64 + row)) * LLC + k0n + j * 8;
            __builtin_amdgcn_global_load_lds((const AS1 unsigned int*)gv,
                                             (AS3 unsigned int*)(Vn + (w * 64) * 8), 16, 0, 0);
        }

        v4f S[4];
#pragma unroll
        for (int ns = 0; ns < 4; ns++) S[ns] = (v4f){0.f, 0.f, 0.f, 0.f};
        __builtin_amdgcn_s_setprio(1);
#pragma unroll
        for (int kk = 0; kk < 2; kk++) {
#pragma unroll
            for (int ns = 0; ns < 4; ns++) {
                v8s kf = *(const v8s*)&Kc[(ns * 16 + m15) * 64 +
                                          (((kk * 4 + quad) ^ sw) * 8)];
                S[ns] = __builtin_amdgcn_mfma_f32_16x16x32_bf16(qa[kk], kf, S[ns], 0, 0, 0);
            }
        }
        __builtin_amdgcn_s_setprio(0);

#pragma unroll
        for (int r = 0; r < 4; r++) {
            int prow = w * 16 + quad * 4 + r;
            float e0 = __builtin_amdgcn_exp2f(S[0][r]);
            float e1 = __builtin_amdgcn_exp2f(S[1][r]);
            float e2 = __builtin_amdgcn_exp2f(S[2][r]);
            float e3 = __builtin_amdgcn_exp2f(S[3][r]);
            uint2 pk;
            pk.x = pk2bf(e0, e1);
            pk.y = pk2bf(e2, e3);
            *(uint2*)&PQ[prow * 72 + 4 * m15] = pk;
        }

        __builtin_amdgcn_s_setprio(1);
#pragma unroll
        for (int kk = 0; kk < 2; kk++) {
            v8s a0 = *(const v8s*)&PQ[(w * 16 + m15) * 72 + kk * 32 + quad * 8];
            lacc = __builtin_amdgcn_mfma_f32_16x16x32_bf16(a0, ones, lacc, 0, 0, 0);
#pragma unroll
            for (int db = 0; db < 4; db++) {
                v8s vf = *(const v8s*)&Vc[(db * 16 + m15) * 64 +
                                          (((kk * 4 + quad) ^ sw) * 8)];
                O[db] = __builtin_amdgcn_mfma_f32_16x16x32_bf16(a0, vf, O[db], 0, 0, 0);
            }
        }
        __builtin_amdgcn_s_setprio(0);
        __syncthreads();
    }

#pragma unroll
    for (int r = 0; r < 4; r++) {
        float inv = 1.f / lacc[r];
        int row = q0 + w * 16 + quad * 4 + r;
#pragma unroll
        for (int db = 0; db < 4; db++) {
            X[((size_t)(b * LLC + row)) * D_MODELC + hd + db * 16 + m15] =
                f2bf(O[db][r] * inv);
        }
    }
}

extern "C" void kernel_launch(void* const* d_in, const int* in_sizes, int n_in,
                              void* d_out, int out_size, void* d_ws, size_t ws_size,
                              hipStream_t stream) {
    const float* q = (const float*)d_in[0];
    const float* k = (const float*)d_in[1];
    const float* v = (const float*)d_in[2];
    const float* w_q = (const float*)d_in[3];
    const float* b_q = (const float*)d_in[4];
    const float* w_k = (const float*)d_in[5];
    const float* b_k = (const float*)d_in[6];
    const float* w_v = (const float*)d_in[7];
    const float* b_v = (const float*)d_in[8];
    const float* w_o = (const float*)d_in[9];
    const float* b_o = (const float*)d_in[10];

    const size_t elems = (size_t)MMC * D_MODELC;  // 4M elems = 8MB bf16
    unsigned short* Qp = (unsigned short*)d_ws;   // X aliases Qp (see attn)
    unsigned short* Kp = Qp + elems;
    unsigned short* Vp = Kp + elems;              // unused (V writes go to Vt)
    unsigned short* Wt = Vp + elems;  // 4 x 1024x1024 bf16 = 8MB (q,k,v,o)
    unsigned short* X = Qp;
    unsigned short* Vt = (unsigned short*)d_out;  // scratch until final GEMM

    const float QSCALE = 0.125f * 1.44269504088896340736f;  // 1/sqrt(64)*log2(e)

    wtrans<<<dim3(16, 16, 4), 256, 0, stream>>>(w_q, w_k, w_v, w_o, Wt);

    // QKV: 3 segs x 64 m-tiles x 8 n-blocks = 1536 blocks, MT=64 BK=128.
    // seg==2 (V) writes directly into Vt layout (d_out scratch) via LDS
    // transpose epilogue.
    gemm_tile<64, 128, 3, true, false, true><<<1536, 256, 0, stream>>>(
        q, k, v, Wt, b_q, b_k, b_v, Qp, Kp, Vt, QSCALE, 1.f, 1.f);

    // attn: flat 512 blocks, XCD-clustered (4 bh per XCD, 16 q-tiles each)
    attn_mfma<<<512, 512, 0, stream>>>(Qp, Kp, Vt, X);

    // final: 1 seg x 64 m-tiles x 8 n-blocks = 512 blocks, MT=64 BK=128
    gemm_tile<64, 128, 1, false, true, false><<<512, 256, 0, stream>>>(
        X, X, X, Wt + (size_t)3 * D_MODELC * D_MODELC, b_o, b_o, b_o,
        d_out, d_out, d_out, 1.f, 1.f, 1.f);
}